// Round 1
// baseline (3193.782 us; speedup 1.0000x reference)
//
#include <hip/hip_runtime.h>
#include <math.h>

#define H 64
#define NODE_IN 128
#define EDGE_IN 16
#define N_NODES 40000
#define N_EDGES 80000
#define N_GRAPHS 256
#define READOUT 1024
#define D2 128   // 2H
#define QS 256   // 4H

__device__ __forceinline__ float sigmoidf_(float x){ return 1.0f/(1.0f + expf(-x)); }

// ---------------- projection: x0 = relu(nf @ Wp^T + bp); h = x0 ----------------
__global__ __launch_bounds__(256) void proj_kernel(
    const float* __restrict__ nf, const float* __restrict__ Wp,
    const float* __restrict__ bp, float* __restrict__ x0, float* __restrict__ h){
  __shared__ float nf_s[4][NODE_IN];
  int t = threadIdx.x;
  int nb = blockIdx.x * 4;
  for (int idx = t; idx < 4*NODE_IN; idx += 256){
    int nl = idx >> 7, k = idx & 127;
    nf_s[nl][k] = nf[(size_t)(nb + nl)*NODE_IN + k];
  }
  __syncthreads();
  int nl = t >> 6, o = t & 63;
  const float4* wr = (const float4*)(Wp + (size_t)o*NODE_IN);
  const float4* ar = (const float4*)nf_s[nl];
  float acc = bp[o];
  #pragma unroll
  for (int k4 = 0; k4 < 32; ++k4){
    float4 w = wr[k4]; float4 a = ar[k4];
    acc += a.x*w.x + a.y*w.y + a.z*w.z + a.w*w.w;
  }
  acc = fmaxf(acc, 0.0f);
  int n = nb + nl;
  x0[(size_t)n*H + o] = acc;
  h [(size_t)n*H + o] = acc;
}

// ---------------- fused edge message + scatter ----------------
// msg[e,o] = sum_h x[src_e,h] * ( dot16(ef[e], W_edge[h*64+o]) + b_edge[h*64+o] )
// 64 edges per block; thread handles 4 edges x 4 outputs; W_edge tiled in LDS.
__global__ __launch_bounds__(256) void edge_msg_kernel(
    const float* __restrict__ x, const float* __restrict__ ef,
    const int* __restrict__ src, const int* __restrict__ dst,
    const float* __restrict__ We, const float* __restrict__ be,
    float* __restrict__ agg){
  __shared__ float x_s[64][H+1];
  __shared__ float w_s[256][20];   // pad 20 keeps float4 alignment, 2-way banks max
  __shared__ float b_s[256];
  __shared__ int src_s[64], dst_s[64];
  int t = threadIdx.x;
  int ebase = blockIdx.x * 64;
  if (t < 64){ src_s[t] = src[ebase + t]; dst_s[t] = dst[ebase + t]; }
  __syncthreads();
  for (int idx = t; idx < 64*H; idx += 256){
    int e = idx >> 6, hh = idx & 63;
    x_s[e][hh] = x[(size_t)src_s[e]*H + hh];
  }
  int eg = t & 15;       // 16 edge-groups of 4 edges
  int og = t >> 4;       // 16 output-groups of 4 outputs
  // edge features in registers (4 edges x 16)
  float efr[4][16];
  #pragma unroll
  for (int j = 0; j < 4; ++j){
    const float4* p = (const float4*)(ef + (size_t)(ebase + eg*4 + j)*EDGE_IN);
    #pragma unroll
    for (int q = 0; q < 4; ++q){
      float4 v = p[q];
      efr[j][q*4+0] = v.x; efr[j][q*4+1] = v.y;
      efr[j][q*4+2] = v.z; efr[j][q*4+3] = v.w;
    }
  }
  float acc[4][4];
  #pragma unroll
  for (int j = 0; j < 4; ++j)
    #pragma unroll
    for (int oo = 0; oo < 4; ++oo) acc[j][oo] = 0.0f;

  for (int ht = 0; ht < 16; ++ht){
    __syncthreads();
    { // stage 256 rows of W_edge (rows ht*256 .. +255) + bias
      const float4* wp = (const float4*)(We + (size_t)(ht*256 + t)*EDGE_IN);
      float4 a = wp[0], b = wp[1], c = wp[2], d = wp[3];
      float* wr = w_s[t];
      wr[0]=a.x; wr[1]=a.y; wr[2]=a.z; wr[3]=a.w;
      wr[4]=b.x; wr[5]=b.y; wr[6]=b.z; wr[7]=b.w;
      wr[8]=c.x; wr[9]=c.y; wr[10]=c.z; wr[11]=c.w;
      wr[12]=d.x; wr[13]=d.y; wr[14]=d.z; wr[15]=d.w;
      b_s[t] = be[ht*256 + t];
    }
    __syncthreads();
    #pragma unroll
    for (int hl = 0; hl < 4; ++hl){
      int hglob = ht*4 + hl;
      float xv[4];
      #pragma unroll
      for (int j = 0; j < 4; ++j) xv[j] = x_s[eg*4 + j][hglob];
      #pragma unroll
      for (int oo = 0; oo < 4; ++oo){
        int row = hl*64 + og*4 + oo;
        const float4* wp4 = (const float4*)w_s[row];
        float4 w0 = wp4[0], w1 = wp4[1], w2 = wp4[2], w3 = wp4[3];
        float bb = b_s[row];
        #pragma unroll
        for (int j = 0; j < 4; ++j){
          float d = bb;
          d += efr[j][0]*w0.x + efr[j][1]*w0.y + efr[j][2]*w0.z + efr[j][3]*w0.w;
          d += efr[j][4]*w1.x + efr[j][5]*w1.y + efr[j][6]*w1.z + efr[j][7]*w1.w;
          d += efr[j][8]*w2.x + efr[j][9]*w2.y + efr[j][10]*w2.z + efr[j][11]*w2.w;
          d += efr[j][12]*w3.x + efr[j][13]*w3.y + efr[j][14]*w3.z + efr[j][15]*w3.w;
          acc[j][oo] += xv[j]*d;
        }
      }
    }
  }
  #pragma unroll
  for (int j = 0; j < 4; ++j){
    int dn = dst_s[eg*4 + j];
    #pragma unroll
    for (int oo = 0; oo < 4; ++oo)
      atomicAdd(&agg[(size_t)dn*H + og*4 + oo], acc[j][oo]);
  }
}

// ---------------- GRU cell: h = GRU(relu(agg+b_conv), h) ----------------
__global__ __launch_bounds__(256) void gru_kernel(
    const float* __restrict__ agg, const float* __restrict__ bconv,
    const float* __restrict__ Wih, const float* __restrict__ Whh,
    const float* __restrict__ bih, const float* __restrict__ bhh,
    float* __restrict__ h){
  __shared__ float a_s[4][H], h_s[4][H];
  int t = threadIdx.x;
  int nb = blockIdx.x * 4;
  int nl = t >> 6, d = t & 63;
  int n = nb + nl;
  float av = fmaxf(agg[(size_t)n*H + d] + bconv[d], 0.0f);
  float hv = h[(size_t)n*H + d];
  a_s[nl][d] = av; h_s[nl][d] = hv;
  __syncthreads();
  const float4* av4 = (const float4*)a_s[nl];
  const float4* hv4 = (const float4*)h_s[nl];
  float gi[3], gh[3];
  #pragma unroll
  for (int g = 0; g < 3; ++g){
    int row = g*64 + d;
    const float4* wi = (const float4*)(Wih + (size_t)row*H);
    const float4* wh = (const float4*)(Whh + (size_t)row*H);
    float si = bih[row], sh = bhh[row];
    #pragma unroll
    for (int k4 = 0; k4 < 16; ++k4){
      float4 w1 = wi[k4], w2 = wh[k4];
      float4 aa = av4[k4], hh = hv4[k4];
      si += aa.x*w1.x + aa.y*w1.y + aa.z*w1.z + aa.w*w1.w;
      sh += hh.x*w2.x + hh.y*w2.y + hh.z*w2.z + hh.w*w2.w;
    }
    gi[g] = si; gh[g] = sh;
  }
  float r = sigmoidf_(gi[0] + gh[0]);
  float z = sigmoidf_(gi[1] + gh[1]);
  float nn = tanhf(gi[2] + r*gh[2]);
  float hnew = (1.0f - z)*nn + z*hv;
  h[(size_t)n*H + d] = hnew;
}

// ---------------- Set2Set LSTM cell (one block per graph, 128 threads) ----------------
__global__ __launch_bounds__(128) void lstm_kernel(
    const float* __restrict__ qstar, const float* __restrict__ Wih,
    const float* __restrict__ Whh, const float* __restrict__ bih,
    const float* __restrict__ bhh, float* __restrict__ hl, float* __restrict__ cl){
  __shared__ float q_s[QS], h_s[D2];
  int g = blockIdx.x, t = threadIdx.x;
  q_s[t]       = qstar[(size_t)g*QS + t];
  q_s[t + 128] = qstar[(size_t)g*QS + t + 128];
  h_s[t]       = hl[(size_t)g*D2 + t];
  __syncthreads();
  const float4* q4 = (const float4*)q_s;
  const float4* h4 = (const float4*)h_s;
  float gv[4];
  #pragma unroll
  for (int gg = 0; gg < 4; ++gg){
    int row = gg*128 + t;
    const float4* wi = (const float4*)(Wih + (size_t)row*QS);
    const float4* wh = (const float4*)(Whh + (size_t)row*D2);
    float s = bih[row] + bhh[row];
    #pragma unroll
    for (int k4 = 0; k4 < 64; ++k4){
      float4 w = wi[k4]; float4 q = q4[k4];
      s += q.x*w.x + q.y*w.y + q.z*w.z + q.w*w.w;
    }
    #pragma unroll
    for (int k4 = 0; k4 < 32; ++k4){
      float4 w = wh[k4]; float4 hh = h4[k4];
      s += hh.x*w.x + hh.y*w.y + hh.z*w.z + hh.w*w.w;
    }
    gv[gg] = s;
  }
  float ig = sigmoidf_(gv[0]);
  float fg = sigmoidf_(gv[1]);
  float gg_ = tanhf(gv[2]);
  float og = sigmoidf_(gv[3]);
  float c = fg*cl[(size_t)g*D2 + t] + ig*gg_;
  float hn = og*tanhf(c);
  cl[(size_t)g*D2 + t] = c;
  hl[(size_t)g*D2 + t] = hn;
}

// ---------------- attention + pooling (one block per graph) ----------------
// graphs are contiguous node ranges: n in [ceil(g*N/B), ceil((g+1)*N/B))
__global__ __launch_bounds__(256) void attn_kernel(
    const float* __restrict__ x0, const float* __restrict__ h,
    const float* __restrict__ hl, float* __restrict__ qstar){
  __shared__ float q_s[D2];
  __shared__ float red[256];
  __shared__ float alpha_s[160];
  int g = blockIdx.x, t = threadIdx.x;
  int n0 = (g*N_NODES + N_GRAPHS - 1)/N_GRAPHS;
  int n1 = ((g+1)*N_NODES + N_GRAPHS - 1)/N_GRAPHS;
  int cnt = n1 - n0;
  if (t < D2) q_s[t] = hl[(size_t)g*D2 + t];
  __syncthreads();
  float e = -1e30f, exv = 0.0f;
  int n = n0 + t;
  if (t < cnt){
    const float4* xr = (const float4*)(x0 + (size_t)n*H);
    const float4* hr = (const float4*)(h  + (size_t)n*H);
    const float4* q1 = (const float4*)q_s;
    const float4* q2 = (const float4*)(q_s + H);
    float s = 0.0f;
    #pragma unroll
    for (int k4 = 0; k4 < 16; ++k4){
      float4 a = xr[k4], b = q1[k4];
      s += a.x*b.x + a.y*b.y + a.z*b.z + a.w*b.w;
    }
    #pragma unroll
    for (int k4 = 0; k4 < 16; ++k4){
      float4 a = hr[k4], b = q2[k4];
      s += a.x*b.x + a.y*b.y + a.z*b.z + a.w*b.w;
    }
    e = s;
  }
  red[t] = e; __syncthreads();
  for (int off = 128; off >= 1; off >>= 1){
    if (t < off) red[t] = fmaxf(red[t], red[t+off]);
    __syncthreads();
  }
  float m = red[0];
  __syncthreads();
  exv = (t < cnt) ? expf(e - m) : 0.0f;
  red[t] = exv; __syncthreads();
  for (int off = 128; off >= 1; off >>= 1){
    if (t < off) red[t] += red[t+off];
    __syncthreads();
  }
  float denom = red[0];
  __syncthreads();
  if (t < cnt) alpha_s[t] = exv / denom;
  __syncthreads();
  if (t < D2){
    const float* base = (t < H) ? x0 : h;
    int k = (t < H) ? t : (t - H);
    float acc = 0.0f;
    for (int i = 0; i < cnt; ++i)
      acc += alpha_s[i] * base[(size_t)(n0 + i)*H + k];
    qstar[(size_t)g*QS + t]      = q_s[t];   // q half
    qstar[(size_t)g*QS + D2 + t] = acc;      // r_b half
  }
}

// ---------------- readout: out = PReLU(qstar @ Wsp^T + bsp) ----------------
__global__ __launch_bounds__(256) void out_kernel(
    const float* __restrict__ qstar, const float* __restrict__ Wsp,
    const float* __restrict__ bsp, const float* __restrict__ prelu,
    float* __restrict__ out){
  __shared__ float q_s[QS];
  int g = blockIdx.x & 255;
  int jb = blockIdx.x >> 8;
  int t = threadIdx.x;
  q_s[t] = qstar[(size_t)g*QS + t];
  __syncthreads();
  int j = jb*256 + t;
  const float4* w = (const float4*)(Wsp + (size_t)j*QS);
  const float4* q4 = (const float4*)q_s;
  float acc = bsp[j];
  #pragma unroll
  for (int k4 = 0; k4 < 64; ++k4){
    float4 wv = w[k4]; float4 qv = q4[k4];
    acc += qv.x*wv.x + qv.y*wv.y + qv.z*wv.z + qv.w*wv.w;
  }
  float pw = prelu[0];
  out[(size_t)g*READOUT + j] = (acc >= 0.0f) ? acc : pw*acc;
}

extern "C" void kernel_launch(void* const* d_in, const int* in_sizes, int n_in,
                              void* d_out, int out_size, void* d_ws, size_t ws_size,
                              hipStream_t stream) {
  const float* node_feats = (const float*)d_in[0];
  const float* edge_feats = (const float*)d_in[1];
  const int*   esrc       = (const int*)d_in[2];
  const int*   edst       = (const int*)d_in[3];
  // d_in[4] = node_graph_ids (contiguous ranges; computed arithmetically)
  const float* Wproj = (const float*)d_in[5];
  const float* bproj = (const float*)d_in[6];
  const float* Wedge = (const float*)d_in[7];
  const float* bedge = (const float*)d_in[8];
  const float* bconv = (const float*)d_in[9];
  const float* gWih  = (const float*)d_in[10];
  const float* gWhh  = (const float*)d_in[11];
  const float* gbih  = (const float*)d_in[12];
  const float* gbhh  = (const float*)d_in[13];
  const float* lWih  = (const float*)d_in[14];
  const float* lWhh  = (const float*)d_in[15];
  const float* lbih  = (const float*)d_in[16];
  const float* lbhh  = (const float*)d_in[17];
  const float* Wsp   = (const float*)d_in[18];
  const float* bsp   = (const float*)d_in[19];
  const float* prelu = (const float*)d_in[20];

  float* ws    = (float*)d_ws;
  float* x0    = ws;                 // 2,560,000
  float* h     = ws + 2560000;       // 2,560,000
  float* agg   = ws + 5120000;       // 2,560,000
  float* qstar = ws + 7680000;       // 65,536
  float* hl    = qstar + 65536;      // 32,768
  float* cl    = hl + 32768;         // 32,768

  hipMemsetAsync(qstar, 0, (65536 + 32768 + 32768)*sizeof(float), stream);

  proj_kernel<<<N_NODES/4, 256, 0, stream>>>(node_feats, Wproj, bproj, x0, h);

  for (int s = 0; s < 3; ++s){
    hipMemsetAsync(agg, 0, (size_t)N_NODES*H*sizeof(float), stream);
    edge_msg_kernel<<<N_EDGES/64, 256, 0, stream>>>(h, edge_feats, esrc, edst, Wedge, bedge, agg);
    gru_kernel<<<N_NODES/4, 256, 0, stream>>>(agg, bconv, gWih, gWhh, gbih, gbhh, h);
  }

  for (int s = 0; s < 3; ++s){
    lstm_kernel<<<N_GRAPHS, 128, 0, stream>>>(qstar, lWih, lWhh, lbih, lbhh, hl, cl);
    attn_kernel<<<N_GRAPHS, 256, 0, stream>>>(x0, h, hl, qstar);
  }

  out_kernel<<<4*N_GRAPHS, 256, 0, stream>>>(qstar, Wsp, bsp, prelu, (float*)d_out);
}

// Round 2
// 1250.518 us; speedup vs baseline: 2.5540x; 2.5540x over previous
//
#include <hip/hip_runtime.h>
#include <math.h>

#define H 64
#define NODE_IN 128
#define EDGE_IN 16
#define N_NODES 40000
#define N_EDGES 80000
#define N_GRAPHS 256
#define READOUT 1024
#define D2 128   // 2H
#define QS 256   // 4H

__device__ __forceinline__ float sigmoidf_(float x){ return 1.0f/(1.0f + expf(-x)); }

// ==================== proj GEMM: x0 = relu(nf @ Wp^T + bp); h = x0 ====================
// M=40000 (64/block), N=64, K=128
__global__ __launch_bounds__(256) void proj_mm(
    const float* __restrict__ nf, const float* __restrict__ Wp,
    const float* __restrict__ bp, float* __restrict__ x0, float* __restrict__ h){
  __shared__ float A_s[NODE_IN][64];   // [k][n] 32KB
  __shared__ float B_s[NODE_IN][64];   // [k][c] 32KB
  int t = threadIdx.x;
  int nb = blockIdx.x * 64;
  // stage A transposed: coalesced global read, scatter LDS write
  #pragma unroll
  for (int p = 0; p < 8; ++p){
    int idx = p*256 + t;          // 0..2047 float4s over [64n][32k4]
    int n = idx >> 5, k4 = idx & 31;
    float4 v = ((const float4*)(nf + (size_t)(nb+n)*NODE_IN))[k4];
    A_s[k4*4+0][n]=v.x; A_s[k4*4+1][n]=v.y; A_s[k4*4+2][n]=v.z; A_s[k4*4+3][n]=v.w;
  }
  // stage B transposed: B_s[k][c] = Wp[c*128+k]; c in low bits (conflict-free LDS writes)
  #pragma unroll
  for (int p = 0; p < 8; ++p){
    int idx = p*256 + t;          // [64c][32k4]
    int c = idx & 63, k4 = idx >> 6;
    float4 v = ((const float4*)(Wp + (size_t)c*NODE_IN))[k4];
    B_s[k4*4+0][c]=v.x; B_s[k4*4+1][c]=v.y; B_s[k4*4+2][c]=v.z; B_s[k4*4+3][c]=v.w;
  }
  __syncthreads();
  int eg = t & 15, cg = t >> 4;   // 4 nodes, 4 cols each
  float acc[4][4] = {};
  #pragma unroll 4
  for (int k = 0; k < NODE_IN; ++k){
    float4 a = *(const float4*)&A_s[k][eg*4];
    float4 b = *(const float4*)&B_s[k][cg*4];
    float av[4] = {a.x,a.y,a.z,a.w};
    float bv[4] = {b.x,b.y,b.z,b.w};
    #pragma unroll
    for (int j = 0; j < 4; ++j)
      #pragma unroll
      for (int c = 0; c < 4; ++c) acc[j][c] += av[j]*bv[c];
  }
  float4 bb = ((const float4*)bp)[cg];
  float bv[4] = {bb.x,bb.y,bb.z,bb.w};
  #pragma unroll
  for (int j = 0; j < 4; ++j){
    int n = nb + eg*4 + j;
    float4 o;
    o.x = fmaxf(acc[j][0]+bv[0], 0.f);
    o.y = fmaxf(acc[j][1]+bv[1], 0.f);
    o.z = fmaxf(acc[j][2]+bv[2], 0.f);
    o.w = fmaxf(acc[j][3]+bv[3], 0.f);
    *(float4*)(x0 + (size_t)n*H + cg*4) = o;
    *(float4*)(h  + (size_t)n*H + cg*4) = o;
  }
}

// ==================== G GEMM: G[40000x1024] = x @ We_view[64][1024] ====================
// grid (625, 4); tile 64 nodes x 256 cols, K=64 (2 chunks of 32)
__global__ __launch_bounds__(256) void g_mm(
    const float* __restrict__ x, const float* __restrict__ We,
    float* __restrict__ G){
  __shared__ float A_s[64][64];    // [k][n] 16KB
  __shared__ float B_s[32][256];   // [k][c] 32KB
  int t = threadIdx.x;
  int nb = blockIdx.x * 64;
  int cb = blockIdx.y * 256;
  #pragma unroll
  for (int p = 0; p < 4; ++p){
    int idx = p*256 + t;          // [64n][16k4]
    int n = idx >> 4, k4 = idx & 15;
    float4 v = ((const float4*)(x + (size_t)(nb+n)*H))[k4];
    A_s[k4*4+0][n]=v.x; A_s[k4*4+1][n]=v.y; A_s[k4*4+2][n]=v.z; A_s[k4*4+3][n]=v.w;
  }
  int eg = t & 7, cg = t >> 3;    // 8 nodes, 8 cols each
  float acc[8][8] = {};
  #pragma unroll
  for (int kc = 0; kc < 2; ++kc){
    __syncthreads();
    #pragma unroll
    for (int p = 0; p < 8; ++p){
      int idx = p*256 + t;        // [32r][64c4]
      int r = idx >> 6, c4 = idx & 63;
      float4 v = ((const float4*)(We + (size_t)(kc*32+r)*1024 + cb))[c4];
      *(float4*)&B_s[r][c4*4] = v;
    }
    __syncthreads();
    #pragma unroll 2
    for (int r = 0; r < 32; ++r){
      int k = kc*32 + r;
      float4 a0 = *(const float4*)&A_s[k][eg*8];
      float4 a1 = *(const float4*)&A_s[k][eg*8+4];
      float4 b0 = *(const float4*)&B_s[r][cg*8];
      float4 b1 = *(const float4*)&B_s[r][cg*8+4];
      float av[8] = {a0.x,a0.y,a0.z,a0.w,a1.x,a1.y,a1.z,a1.w};
      float bv[8] = {b0.x,b0.y,b0.z,b0.w,b1.x,b1.y,b1.z,b1.w};
      #pragma unroll
      for (int n = 0; n < 8; ++n)
        #pragma unroll
        for (int c = 0; c < 8; ++c) acc[n][c] += av[n]*bv[c];
    }
  }
  #pragma unroll
  for (int n = 0; n < 8; ++n){
    int node = nb + eg*8 + n;
    float* gp = G + (size_t)node*1024 + cb + cg*8;
    *(float4*)gp       = make_float4(acc[n][0],acc[n][1],acc[n][2],acc[n][3]);
    *(float4*)(gp + 4) = make_float4(acc[n][4],acc[n][5],acc[n][6],acc[n][7]);
  }
}

// ==================== P GEMM: P[40000x64] = x @ Bb, Bb[k][c] = b_edge[k*64+c] ====================
__global__ __launch_bounds__(256) void p_mm(
    const float* __restrict__ x, const float* __restrict__ be, float* __restrict__ P){
  __shared__ float A_s[64][64];
  __shared__ float B_s[64][64];
  int t = threadIdx.x;
  int nb = blockIdx.x * 64;
  #pragma unroll
  for (int p = 0; p < 4; ++p){
    int idx = p*256 + t;
    int n = idx >> 4, k4 = idx & 15;
    float4 v = ((const float4*)(x + (size_t)(nb+n)*H))[k4];
    A_s[k4*4+0][n]=v.x; A_s[k4*4+1][n]=v.y; A_s[k4*4+2][n]=v.z; A_s[k4*4+3][n]=v.w;
  }
  #pragma unroll
  for (int p = 0; p < 4; ++p){
    int idx = p*256 + t;          // [64r][16c4]
    int r = idx >> 4, c4 = idx & 15;
    *(float4*)&B_s[r][c4*4] = ((const float4*)(be + (size_t)r*64))[c4];
  }
  __syncthreads();
  int eg = t & 15, cg = t >> 4;
  float acc[4][4] = {};
  #pragma unroll 4
  for (int k = 0; k < 64; ++k){
    float4 a = *(const float4*)&A_s[k][eg*4];
    float4 b = *(const float4*)&B_s[k][cg*4];
    float av[4] = {a.x,a.y,a.z,a.w};
    float bv[4] = {b.x,b.y,b.z,b.w};
    #pragma unroll
    for (int j = 0; j < 4; ++j)
      #pragma unroll
      for (int c = 0; c < 4; ++c) acc[j][c] += av[j]*bv[c];
  }
  #pragma unroll
  for (int j = 0; j < 4; ++j){
    int n = nb + eg*4 + j;
    *(float4*)(P + (size_t)n*H + cg*4) =
      make_float4(acc[j][0],acc[j][1],acc[j][2],acc[j][3]);
  }
}

// ==================== edge apply: one wave per edge ====================
// msg[e,o] = P[src,o] + sum_k ef[e,k]*G[src][o*16+k]; atomic into agg[dst]
__global__ __launch_bounds__(256) void edge_apply(
    const float* __restrict__ G, const float* __restrict__ P,
    const float* __restrict__ ef, const int* __restrict__ src,
    const int* __restrict__ dst, float* __restrict__ agg){
  int lane = threadIdx.x & 63;
  int wid = blockIdx.x * 4 + (threadIdx.x >> 6);
  int nw = gridDim.x * 4;
  for (int e = wid; e < N_EDGES; e += nw){
    int s = src[e], d = dst[e];
    const float4* g4 = (const float4*)(G + (size_t)s*1024 + lane*16);
    float4 g0=g4[0], g1=g4[1], g2=g4[2], g3=g4[3];
    const float4* e4 = (const float4*)(ef + (size_t)e*EDGE_IN);
    float4 f0=e4[0], f1=e4[1], f2=e4[2], f3=e4[3];
    float m = P[(size_t)s*H + lane];
    m = fmaf(f0.x,g0.x, fmaf(f0.y,g0.y, fmaf(f0.z,g0.z, fmaf(f0.w,g0.w, m))));
    m = fmaf(f1.x,g1.x, fmaf(f1.y,g1.y, fmaf(f1.z,g1.z, fmaf(f1.w,g1.w, m))));
    m = fmaf(f2.x,g2.x, fmaf(f2.y,g2.y, fmaf(f2.z,g2.z, fmaf(f2.w,g2.w, m))));
    m = fmaf(f3.x,g3.x, fmaf(f3.y,g3.y, fmaf(f3.z,g3.z, fmaf(f3.w,g3.w, m))));
    atomicAdd(&agg[(size_t)d*H + lane], m);
  }
}

// ==================== Bc pack for GRU GEMM ====================
// Bc[k][c], k<64 from act-part (Wih), k>=64 from h-part (Whh)
// c in [0,128): r|z sum cols (row=c); c in [128,192): gi_n; c in [192,256): gh_n
__global__ __launch_bounds__(256) void build_bc(
    const float* __restrict__ Wih, const float* __restrict__ Whh,
    float* __restrict__ Bc){
  int i = blockIdx.x*256 + threadIdx.x;   // 32768
  int k = i >> 8, c = i & 255;
  float v;
  if (c < 128){
    v = (k < 64) ? Wih[(size_t)c*H + k] : Whh[(size_t)c*H + (k-64)];
  } else if (c < 192){
    int d = c - 128;
    v = (k < 64) ? Wih[(size_t)(128+d)*H + k] : 0.f;
  } else {
    int d = c - 192;
    v = (k < 64) ? 0.f : Whh[(size_t)(128+d)*H + (k-64)];
  }
  Bc[i] = v;
}

// ==================== GRU GEMM: C[40000x256] = [relu(agg+bconv)|h] @ Bc ====================
__global__ __launch_bounds__(256) void gru_mm(
    const float* __restrict__ agg, const float* __restrict__ bconv,
    const float* __restrict__ hm, const float* __restrict__ Bc,
    float* __restrict__ C){
  __shared__ float A_s[128][64];   // 32KB
  __shared__ float B_s[32][256];   // 32KB
  int t = threadIdx.x;
  int nb = blockIdx.x * 64;
  #pragma unroll
  for (int p = 0; p < 4; ++p){
    int idx = p*256 + t;
    int n = idx >> 4, k4 = idx & 15;
    float4 v = ((const float4*)(agg + (size_t)(nb+n)*H))[k4];
    float4 b = ((const float4*)bconv)[k4];
    A_s[k4*4+0][n]=fmaxf(v.x+b.x,0.f); A_s[k4*4+1][n]=fmaxf(v.y+b.y,0.f);
    A_s[k4*4+2][n]=fmaxf(v.z+b.z,0.f); A_s[k4*4+3][n]=fmaxf(v.w+b.w,0.f);
    float4 w = ((const float4*)(hm + (size_t)(nb+n)*H))[k4];
    A_s[64+k4*4+0][n]=w.x; A_s[64+k4*4+1][n]=w.y;
    A_s[64+k4*4+2][n]=w.z; A_s[64+k4*4+3][n]=w.w;
  }
  int eg = t & 7, cg = t >> 3;
  float acc[8][8] = {};
  #pragma unroll
  for (int kc = 0; kc < 4; ++kc){
    __syncthreads();
    #pragma unroll
    for (int p = 0; p < 8; ++p){
      int idx = p*256 + t;
      int r = idx >> 6, c4 = idx & 63;
      *(float4*)&B_s[r][c4*4] = ((const float4*)(Bc + (size_t)(kc*32+r)*256))[c4];
    }
    __syncthreads();
    #pragma unroll 2
    for (int r = 0; r < 32; ++r){
      int k = kc*32 + r;
      float4 a0 = *(const float4*)&A_s[k][eg*8];
      float4 a1 = *(const float4*)&A_s[k][eg*8+4];
      float4 b0 = *(const float4*)&B_s[r][cg*8];
      float4 b1 = *(const float4*)&B_s[r][cg*8+4];
      float av[8] = {a0.x,a0.y,a0.z,a0.w,a1.x,a1.y,a1.z,a1.w};
      float bv[8] = {b0.x,b0.y,b0.z,b0.w,b1.x,b1.y,b1.z,b1.w};
      #pragma unroll
      for (int n = 0; n < 8; ++n)
        #pragma unroll
        for (int c = 0; c < 8; ++c) acc[n][c] += av[n]*bv[c];
    }
  }
  #pragma unroll
  for (int n = 0; n < 8; ++n){
    int node = nb + eg*8 + n;
    float* cp = C + (size_t)node*256 + cg*8;
    *(float4*)cp       = make_float4(acc[n][0],acc[n][1],acc[n][2],acc[n][3]);
    *(float4*)(cp + 4) = make_float4(acc[n][4],acc[n][5],acc[n][6],acc[n][7]);
  }
}

// ==================== GRU combine (elementwise) ====================
__global__ __launch_bounds__(256) void gru_combine(
    const float* __restrict__ C, const float* __restrict__ bih,
    const float* __restrict__ bhh, float* __restrict__ h){
  int i = blockIdx.x*256 + threadIdx.x;   // 640000 float4-groups
  int n = i >> 4, d4 = i & 15;
  float4 c0 = ((const float4*)(C + (size_t)n*256      ))[d4];
  float4 c1 = ((const float4*)(C + (size_t)n*256 +  64))[d4];
  float4 c2 = ((const float4*)(C + (size_t)n*256 + 128))[d4];
  float4 c3 = ((const float4*)(C + (size_t)n*256 + 192))[d4];
  float4 hv = ((const float4*)(h + (size_t)n*H))[d4];
  float4 bi0 = ((const float4*)(bih      ))[d4];
  float4 bh0 = ((const float4*)(bhh      ))[d4];
  float4 bi1 = ((const float4*)(bih +  64))[d4];
  float4 bh1 = ((const float4*)(bhh +  64))[d4];
  float4 bi2 = ((const float4*)(bih + 128))[d4];
  float4 bh2 = ((const float4*)(bhh + 128))[d4];
  float4 o;
  {
    float r = sigmoidf_(c0.x + bi0.x + bh0.x);
    float z = sigmoidf_(c1.x + bi1.x + bh1.x);
    float nn = tanhf(c2.x + bi2.x + r*(c3.x + bh2.x));
    o.x = (1.f - z)*nn + z*hv.x;
  }
  {
    float r = sigmoidf_(c0.y + bi0.y + bh0.y);
    float z = sigmoidf_(c1.y + bi1.y + bh1.y);
    float nn = tanhf(c2.y + bi2.y + r*(c3.y + bh2.y));
    o.y = (1.f - z)*nn + z*hv.y;
  }
  {
    float r = sigmoidf_(c0.z + bi0.z + bh0.z);
    float z = sigmoidf_(c1.z + bi1.z + bh1.z);
    float nn = tanhf(c2.z + bi2.z + r*(c3.z + bh2.z));
    o.z = (1.f - z)*nn + z*hv.z;
  }
  {
    float r = sigmoidf_(c0.w + bi0.w + bh0.w);
    float z = sigmoidf_(c1.w + bi1.w + bh1.w);
    float nn = tanhf(c2.w + bi2.w + r*(c3.w + bh2.w));
    o.w = (1.f - z)*nn + z*hv.w;
  }
  ((float4*)(h + (size_t)n*H))[d4] = o;
}

// ==================== fallback fused edge kernel (tiers B/C) ====================
__global__ __launch_bounds__(256) void edge_msg_kernel(
    const float* __restrict__ x, const float* __restrict__ ef,
    const int* __restrict__ src, const int* __restrict__ dst,
    const float* __restrict__ We, const float* __restrict__ be,
    float* __restrict__ agg){
  __shared__ float x_s[64][H+1];
  __shared__ float w_s[256][20];
  __shared__ float b_s[256];
  __shared__ int src_s[64], dst_s[64];
  int t = threadIdx.x;
  int ebase = blockIdx.x * 64;
  if (t < 64){ src_s[t] = src[ebase + t]; dst_s[t] = dst[ebase + t]; }
  __syncthreads();
  for (int idx = t; idx < 64*H; idx += 256){
    int e = idx >> 6, hh = idx & 63;
    x_s[e][hh] = x[(size_t)src_s[e]*H + hh];
  }
  int eg = t & 15, og = t >> 4;
  float efr[4][16];
  #pragma unroll
  for (int j = 0; j < 4; ++j){
    const float4* p = (const float4*)(ef + (size_t)(ebase + eg*4 + j)*EDGE_IN);
    #pragma unroll
    for (int q = 0; q < 4; ++q){
      float4 v = p[q];
      efr[j][q*4+0]=v.x; efr[j][q*4+1]=v.y; efr[j][q*4+2]=v.z; efr[j][q*4+3]=v.w;
    }
  }
  float acc[4][4] = {};
  for (int ht = 0; ht < 16; ++ht){
    __syncthreads();
    {
      const float4* wp = (const float4*)(We + (size_t)(ht*256 + t)*EDGE_IN);
      float4 a = wp[0], b = wp[1], c = wp[2], d = wp[3];
      float* wr = w_s[t];
      wr[0]=a.x; wr[1]=a.y; wr[2]=a.z; wr[3]=a.w;
      wr[4]=b.x; wr[5]=b.y; wr[6]=b.z; wr[7]=b.w;
      wr[8]=c.x; wr[9]=c.y; wr[10]=c.z; wr[11]=c.w;
      wr[12]=d.x; wr[13]=d.y; wr[14]=d.z; wr[15]=d.w;
      b_s[t] = be[ht*256 + t];
    }
    __syncthreads();
    #pragma unroll
    for (int hl = 0; hl < 4; ++hl){
      int hglob = ht*4 + hl;
      float xv[4];
      #pragma unroll
      for (int j = 0; j < 4; ++j) xv[j] = x_s[eg*4 + j][hglob];
      #pragma unroll
      for (int oo = 0; oo < 4; ++oo){
        int row = hl*64 + og*4 + oo;
        const float4* wp4 = (const float4*)w_s[row];
        float4 w0 = wp4[0], w1 = wp4[1], w2 = wp4[2], w3 = wp4[3];
        float bb = b_s[row];
        #pragma unroll
        for (int j = 0; j < 4; ++j){
          float d = bb;
          d += efr[j][0]*w0.x + efr[j][1]*w0.y + efr[j][2]*w0.z + efr[j][3]*w0.w;
          d += efr[j][4]*w1.x + efr[j][5]*w1.y + efr[j][6]*w1.z + efr[j][7]*w1.w;
          d += efr[j][8]*w2.x + efr[j][9]*w2.y + efr[j][10]*w2.z + efr[j][11]*w2.w;
          d += efr[j][12]*w3.x + efr[j][13]*w3.y + efr[j][14]*w3.z + efr[j][15]*w3.w;
          acc[j][oo] += xv[j]*d;
        }
      }
    }
  }
  #pragma unroll
  for (int j = 0; j < 4; ++j){
    int dn = dst_s[eg*4 + j];
    #pragma unroll
    for (int oo = 0; oo < 4; ++oo)
      atomicAdd(&agg[(size_t)dn*H + og*4 + oo], acc[j][oo]);
  }
}

// ==================== fallback GRU (tier C) ====================
__global__ __launch_bounds__(256) void gru_kernel(
    const float* __restrict__ agg, const float* __restrict__ bconv,
    const float* __restrict__ Wih, const float* __restrict__ Whh,
    const float* __restrict__ bih, const float* __restrict__ bhh,
    float* __restrict__ h){
  __shared__ float a_s[4][H], h_s[4][H];
  int t = threadIdx.x;
  int nb = blockIdx.x * 4;
  int nl = t >> 6, d = t & 63;
  int n = nb + nl;
  float av = fmaxf(agg[(size_t)n*H + d] + bconv[d], 0.0f);
  float hv = h[(size_t)n*H + d];
  a_s[nl][d] = av; h_s[nl][d] = hv;
  __syncthreads();
  const float4* av4 = (const float4*)a_s[nl];
  const float4* hv4 = (const float4*)h_s[nl];
  float gi[3], gh[3];
  #pragma unroll
  for (int g = 0; g < 3; ++g){
    int row = g*64 + d;
    const float4* wi = (const float4*)(Wih + (size_t)row*H);
    const float4* wh = (const float4*)(Whh + (size_t)row*H);
    float si = bih[row], sh = bhh[row];
    #pragma unroll
    for (int k4 = 0; k4 < 16; ++k4){
      float4 w1 = wi[k4], w2 = wh[k4];
      float4 aa = av4[k4], hh = hv4[k4];
      si += aa.x*w1.x + aa.y*w1.y + aa.z*w1.z + aa.w*w1.w;
      sh += hh.x*w2.x + hh.y*w2.y + hh.z*w2.z + hh.w*w2.w;
    }
    gi[g] = si; gh[g] = sh;
  }
  float r = sigmoidf_(gi[0] + gh[0]);
  float z = sigmoidf_(gi[1] + gh[1]);
  float nn = tanhf(gi[2] + r*gh[2]);
  h[(size_t)n*H + d] = (1.0f - z)*nn + z*hv;
}

// ==================== Set2Set LSTM cell ====================
__global__ __launch_bounds__(128) void lstm_kernel(
    const float* __restrict__ qstar, const float* __restrict__ Wih,
    const float* __restrict__ Whh, const float* __restrict__ bih,
    const float* __restrict__ bhh, float* __restrict__ hl, float* __restrict__ cl){
  __shared__ float q_s[QS], h_s[D2];
  int g = blockIdx.x, t = threadIdx.x;
  q_s[t]       = qstar[(size_t)g*QS + t];
  q_s[t + 128] = qstar[(size_t)g*QS + t + 128];
  h_s[t]       = hl[(size_t)g*D2 + t];
  __syncthreads();
  const float4* q4 = (const float4*)q_s;
  const float4* h4 = (const float4*)h_s;
  float gv[4];
  #pragma unroll
  for (int gg = 0; gg < 4; ++gg){
    int row = gg*128 + t;
    const float4* wi = (const float4*)(Wih + (size_t)row*QS);
    const float4* wh = (const float4*)(Whh + (size_t)row*D2);
    float s = bih[row] + bhh[row];
    #pragma unroll
    for (int k4 = 0; k4 < 64; ++k4){
      float4 w = wi[k4]; float4 q = q4[k4];
      s += q.x*w.x + q.y*w.y + q.z*w.z + q.w*w.w;
    }
    #pragma unroll
    for (int k4 = 0; k4 < 32; ++k4){
      float4 w = wh[k4]; float4 hh = h4[k4];
      s += hh.x*w.x + hh.y*w.y + hh.z*w.z + hh.w*w.w;
    }
    gv[gg] = s;
  }
  float ig = sigmoidf_(gv[0]);
  float fg = sigmoidf_(gv[1]);
  float gg_ = tanhf(gv[2]);
  float og = sigmoidf_(gv[3]);
  float c = fg*cl[(size_t)g*D2 + t] + ig*gg_;
  float hn = og*tanhf(c);
  cl[(size_t)g*D2 + t] = c;
  hl[(size_t)g*D2 + t] = hn;
}

// ==================== attention + pooling ====================
__global__ __launch_bounds__(256) void attn_kernel(
    const float* __restrict__ x0, const float* __restrict__ h,
    const float* __restrict__ hl, float* __restrict__ qstar){
  __shared__ float q_s[D2];
  __shared__ float red[256];
  __shared__ float alpha_s[160];
  int g = blockIdx.x, t = threadIdx.x;
  int n0 = (g*N_NODES + N_GRAPHS - 1)/N_GRAPHS;
  int n1 = ((g+1)*N_NODES + N_GRAPHS - 1)/N_GRAPHS;
  int cnt = n1 - n0;
  if (t < D2) q_s[t] = hl[(size_t)g*D2 + t];
  __syncthreads();
  float e = -1e30f, exv = 0.0f;
  int n = n0 + t;
  if (t < cnt){
    const float4* xr = (const float4*)(x0 + (size_t)n*H);
    const float4* hr = (const float4*)(h  + (size_t)n*H);
    const float4* q1 = (const float4*)q_s;
    const float4* q2 = (const float4*)(q_s + H);
    float s = 0.0f;
    #pragma unroll
    for (int k4 = 0; k4 < 16; ++k4){
      float4 a = xr[k4], b = q1[k4];
      s += a.x*b.x + a.y*b.y + a.z*b.z + a.w*b.w;
    }
    #pragma unroll
    for (int k4 = 0; k4 < 16; ++k4){
      float4 a = hr[k4], b = q2[k4];
      s += a.x*b.x + a.y*b.y + a.z*b.z + a.w*b.w;
    }
    e = s;
  }
  red[t] = e; __syncthreads();
  for (int off = 128; off >= 1; off >>= 1){
    if (t < off) red[t] = fmaxf(red[t], red[t+off]);
    __syncthreads();
  }
  float m = red[0];
  __syncthreads();
  exv = (t < cnt) ? expf(e - m) : 0.0f;
  red[t] = exv; __syncthreads();
  for (int off = 128; off >= 1; off >>= 1){
    if (t < off) red[t] += red[t+off];
    __syncthreads();
  }
  float denom = red[0];
  __syncthreads();
  if (t < cnt) alpha_s[t] = exv / denom;
  __syncthreads();
  // pooling: all 256 threads; d = t&127, node parity = t>>7
  {
    int d = t & 127, half = t >> 7;
    const float* base = (d < H) ? x0 : h;
    int kk = d & 63;
    float acc2 = 0.f;
    for (int i = half; i < cnt; i += 2)
      acc2 += alpha_s[i] * base[(size_t)(n0+i)*H + kk];
    red[t] = acc2;
  }
  __syncthreads();
  if (t < D2){
    float v = red[t] + red[t + 128];
    qstar[(size_t)g*QS + t]      = q_s[t];
    qstar[(size_t)g*QS + D2 + t] = v;
  }
}

// ==================== readout ====================
__global__ __launch_bounds__(256) void out_kernel(
    const float* __restrict__ qstar, const float* __restrict__ Wsp,
    const float* __restrict__ bsp, const float* __restrict__ prelu,
    float* __restrict__ out){
  __shared__ float q_s[QS];
  int g = blockIdx.x & 255;
  int jb = blockIdx.x >> 8;
  int t = threadIdx.x;
  q_s[t] = qstar[(size_t)g*QS + t];
  __syncthreads();
  int j = jb*256 + t;
  const float4* w = (const float4*)(Wsp + (size_t)j*QS);
  const float4* q4 = (const float4*)q_s;
  float acc = bsp[j];
  #pragma unroll
  for (int k4 = 0; k4 < 64; ++k4){
    float4 wv = w[k4]; float4 qv = q4[k4];
    acc += qv.x*wv.x + qv.y*wv.y + qv.z*wv.z + qv.w*wv.w;
  }
  float pw = prelu[0];
  out[(size_t)g*READOUT + j] = (acc >= 0.0f) ? acc : pw*acc;
}

extern "C" void kernel_launch(void* const* d_in, const int* in_sizes, int n_in,
                              void* d_out, int out_size, void* d_ws, size_t ws_size,
                              hipStream_t stream) {
  const float* node_feats = (const float*)d_in[0];
  const float* edge_feats = (const float*)d_in[1];
  const int*   esrc       = (const int*)d_in[2];
  const int*   edst       = (const int*)d_in[3];
  const float* Wproj = (const float*)d_in[5];
  const float* bproj = (const float*)d_in[6];
  const float* Wedge = (const float*)d_in[7];
  const float* bedge = (const float*)d_in[8];
  const float* bconv = (const float*)d_in[9];
  const float* gWih  = (const float*)d_in[10];
  const float* gWhh  = (const float*)d_in[11];
  const float* gbih  = (const float*)d_in[12];
  const float* gbhh  = (const float*)d_in[13];
  const float* lWih  = (const float*)d_in[14];
  const float* lWhh  = (const float*)d_in[15];
  const float* lbih  = (const float*)d_in[16];
  const float* lbhh  = (const float*)d_in[17];
  const float* Wsp   = (const float*)d_in[18];
  const float* bsp   = (const float*)d_in[19];
  const float* prelu = (const float*)d_in[20];

  float* ws    = (float*)d_ws;
  float* x0    = ws;                     // 2,560,000
  float* h     = ws + 2560000;           // 2,560,000
  float* agg   = ws + 5120000;           // 2,560,000
  float* qstar = ws + 7680000;           // 65,536
  float* hl    = qstar + 65536;          // 32,768
  float* cl    = hl + 32768;             // 32,768
  float* Bc    = cl + 32768;             // 32,768   (ends 7,843,840)
  float* P     = Bc + 32768;             // 2,560,000
  float* G     = P + 2560000;            // 40,960,000 (ends 51,363,840)

  // tier by available scratch
  const size_t needA = 51363840ull * sizeof(float);  // ~205.5 MB
  const size_t needB = 18083840ull * sizeof(float);  // ~72.3 MB (C at P's slot)
  int tier = (ws_size >= needA) ? 0 : ((ws_size >= needB) ? 1 : 2);
  float* C = (tier == 0) ? G : P;        // C: 40000x256 (reuses dead G in tier 0)

  hipMemsetAsync(qstar, 0, (65536 + 32768 + 32768)*sizeof(float), stream);

  proj_mm<<<N_NODES/64, 256, 0, stream>>>(node_feats, Wproj, bproj, x0, h);

  if (tier <= 1)
    build_bc<<<128, 256, 0, stream>>>(gWih, gWhh, Bc);

  for (int s = 0; s < 3; ++s){
    if (tier == 0){
      g_mm<<<dim3(N_NODES/64, 4), 256, 0, stream>>>(h, Wedge, G);
      p_mm<<<N_NODES/64, 256, 0, stream>>>(h, bedge, P);
      hipMemsetAsync(agg, 0, (size_t)N_NODES*H*sizeof(float), stream);
      edge_apply<<<2500, 256, 0, stream>>>(G, P, edge_feats, esrc, edst, agg);
    } else {
      hipMemsetAsync(agg, 0, (size_t)N_NODES*H*sizeof(float), stream);
      edge_msg_kernel<<<N_EDGES/64, 256, 0, stream>>>(h, edge_feats, esrc, edst, Wedge, bedge, agg);
    }
    if (tier <= 1){
      gru_mm<<<N_NODES/64, 256, 0, stream>>>(agg, bconv, h, Bc, C);
      gru_combine<<<N_NODES*H/4/256, 256, 0, stream>>>(C, gbih, gbhh, h);
    } else {
      gru_kernel<<<N_NODES/4, 256, 0, stream>>>(agg, bconv, gWih, gWhh, gbih, gbhh, h);
    }
  }

  for (int s = 0; s < 3; ++s){
    lstm_kernel<<<N_GRAPHS, 128, 0, stream>>>(qstar, lWih, lWhh, lbih, lbhh, hl, cl);
    attn_kernel<<<N_GRAPHS, 256, 0, stream>>>(x0, h, hl, qstar);
  }

  out_kernel<<<4*N_GRAPHS, 256, 0, stream>>>(qstar, Wsp, bsp, prelu, (float*)d_out);
}

// Round 3
// 942.055 us; speedup vs baseline: 3.3902x; 1.3274x over previous
//
#include <hip/hip_runtime.h>
#include <math.h>

#define H 64
#define NODE_IN 128
#define EDGE_IN 16
#define N_NODES 40000
#define N_EDGES 80000
#define N_GRAPHS 256
#define READOUT 1024
#define D2 128   // 2H
#define QS 256   // 4H

__device__ __forceinline__ float sigmoidf_(float x){ return 1.0f/(1.0f + expf(-x)); }

// ==================== proj GEMM: x0 = relu(nf @ Wp^T + bp); h = x0 ====================
__global__ __launch_bounds__(256) void proj_mm(
    const float* __restrict__ nf, const float* __restrict__ Wp,
    const float* __restrict__ bp, float* __restrict__ x0, float* __restrict__ h){
  __shared__ float A_s[NODE_IN][64];
  __shared__ float B_s[NODE_IN][64];
  int t = threadIdx.x;
  int nb = blockIdx.x * 64;
  #pragma unroll
  for (int p = 0; p < 8; ++p){
    int idx = p*256 + t;
    int n = idx >> 5, k4 = idx & 31;
    float4 v = ((const float4*)(nf + (size_t)(nb+n)*NODE_IN))[k4];
    A_s[k4*4+0][n]=v.x; A_s[k4*4+1][n]=v.y; A_s[k4*4+2][n]=v.z; A_s[k4*4+3][n]=v.w;
  }
  #pragma unroll
  for (int p = 0; p < 8; ++p){
    int idx = p*256 + t;
    int c = idx & 63, k4 = idx >> 6;
    float4 v = ((const float4*)(Wp + (size_t)c*NODE_IN))[k4];
    B_s[k4*4+0][c]=v.x; B_s[k4*4+1][c]=v.y; B_s[k4*4+2][c]=v.z; B_s[k4*4+3][c]=v.w;
  }
  __syncthreads();
  int eg = t & 15, cg = t >> 4;
  float acc[4][4] = {};
  #pragma unroll 4
  for (int k = 0; k < NODE_IN; ++k){
    float4 a = *(const float4*)&A_s[k][eg*4];
    float4 b = *(const float4*)&B_s[k][cg*4];
    float av[4] = {a.x,a.y,a.z,a.w};
    float bv[4] = {b.x,b.y,b.z,b.w};
    #pragma unroll
    for (int j = 0; j < 4; ++j)
      #pragma unroll
      for (int c = 0; c < 4; ++c) acc[j][c] += av[j]*bv[c];
  }
  float4 bb = ((const float4*)bp)[cg];
  float bv[4] = {bb.x,bb.y,bb.z,bb.w};
  #pragma unroll
  for (int j = 0; j < 4; ++j){
    int n = nb + eg*4 + j;
    float4 o;
    o.x = fmaxf(acc[j][0]+bv[0], 0.f);
    o.y = fmaxf(acc[j][1]+bv[1], 0.f);
    o.z = fmaxf(acc[j][2]+bv[2], 0.f);
    o.w = fmaxf(acc[j][3]+bv[3], 0.f);
    *(float4*)(x0 + (size_t)n*H + cg*4) = o;
    *(float4*)(h  + (size_t)n*H + cg*4) = o;
  }
}

// ==================== G GEMM: G[40000x1024] = x @ We_view[64][1024] ====================
__global__ __launch_bounds__(256) void g_mm(
    const float* __restrict__ x, const float* __restrict__ We,
    float* __restrict__ G){
  __shared__ float A_s[64][64];
  __shared__ float B_s[32][256];
  int t = threadIdx.x;
  int nb = blockIdx.x * 64;
  int cb = blockIdx.y * 256;
  #pragma unroll
  for (int p = 0; p < 4; ++p){
    int idx = p*256 + t;
    int n = idx >> 4, k4 = idx & 15;
    float4 v = ((const float4*)(x + (size_t)(nb+n)*H))[k4];
    A_s[k4*4+0][n]=v.x; A_s[k4*4+1][n]=v.y; A_s[k4*4+2][n]=v.z; A_s[k4*4+3][n]=v.w;
  }
  int eg = t & 7, cg = t >> 3;
  float acc[8][8] = {};
  #pragma unroll
  for (int kc = 0; kc < 2; ++kc){
    __syncthreads();
    #pragma unroll
    for (int p = 0; p < 8; ++p){
      int idx = p*256 + t;
      int r = idx >> 6, c4 = idx & 63;
      float4 v = ((const float4*)(We + (size_t)(kc*32+r)*1024 + cb))[c4];
      *(float4*)&B_s[r][c4*4] = v;
    }
    __syncthreads();
    #pragma unroll 2
    for (int r = 0; r < 32; ++r){
      int k = kc*32 + r;
      float4 a0 = *(const float4*)&A_s[k][eg*8];
      float4 a1 = *(const float4*)&A_s[k][eg*8+4];
      float4 b0 = *(const float4*)&B_s[r][cg*8];
      float4 b1 = *(const float4*)&B_s[r][cg*8+4];
      float av[8] = {a0.x,a0.y,a0.z,a0.w,a1.x,a1.y,a1.z,a1.w};
      float bv[8] = {b0.x,b0.y,b0.z,b0.w,b1.x,b1.y,b1.z,b1.w};
      #pragma unroll
      for (int n = 0; n < 8; ++n)
        #pragma unroll
        for (int c = 0; c < 8; ++c) acc[n][c] += av[n]*bv[c];
    }
  }
  #pragma unroll
  for (int n = 0; n < 8; ++n){
    int node = nb + eg*8 + n;
    float* gp = G + (size_t)node*1024 + cb + cg*8;
    *(float4*)gp       = make_float4(acc[n][0],acc[n][1],acc[n][2],acc[n][3]);
    *(float4*)(gp + 4) = make_float4(acc[n][4],acc[n][5],acc[n][6],acc[n][7]);
  }
}

// ==================== P GEMM: P[40000x64] = x @ Bb ====================
__global__ __launch_bounds__(256) void p_mm(
    const float* __restrict__ x, const float* __restrict__ be, float* __restrict__ P){
  __shared__ float A_s[64][64];
  __shared__ float B_s[64][64];
  int t = threadIdx.x;
  int nb = blockIdx.x * 64;
  #pragma unroll
  for (int p = 0; p < 4; ++p){
    int idx = p*256 + t;
    int n = idx >> 4, k4 = idx & 15;
    float4 v = ((const float4*)(x + (size_t)(nb+n)*H))[k4];
    A_s[k4*4+0][n]=v.x; A_s[k4*4+1][n]=v.y; A_s[k4*4+2][n]=v.z; A_s[k4*4+3][n]=v.w;
  }
  #pragma unroll
  for (int p = 0; p < 4; ++p){
    int idx = p*256 + t;
    int r = idx >> 4, c4 = idx & 15;
    *(float4*)&B_s[r][c4*4] = ((const float4*)(be + (size_t)r*64))[c4];
  }
  __syncthreads();
  int eg = t & 15, cg = t >> 4;
  float acc[4][4] = {};
  #pragma unroll 4
  for (int k = 0; k < 64; ++k){
    float4 a = *(const float4*)&A_s[k][eg*4];
    float4 b = *(const float4*)&B_s[k][cg*4];
    float av[4] = {a.x,a.y,a.z,a.w};
    float bv[4] = {b.x,b.y,b.z,b.w};
    #pragma unroll
    for (int j = 0; j < 4; ++j)
      #pragma unroll
      for (int c = 0; c < 4; ++c) acc[j][c] += av[j]*bv[c];
  }
  #pragma unroll
  for (int j = 0; j < 4; ++j){
    int n = nb + eg*4 + j;
    *(float4*)(P + (size_t)n*H + cg*4) =
      make_float4(acc[j][0],acc[j][1],acc[j][2],acc[j][3]);
  }
}

// ==================== edge apply ====================
__global__ __launch_bounds__(256) void edge_apply(
    const float* __restrict__ G, const float* __restrict__ P,
    const float* __restrict__ ef, const int* __restrict__ src,
    const int* __restrict__ dst, float* __restrict__ agg){
  int lane = threadIdx.x & 63;
  int wid = blockIdx.x * 4 + (threadIdx.x >> 6);
  int nw = gridDim.x * 4;
  for (int e = wid; e < N_EDGES; e += nw){
    int s = src[e], d = dst[e];
    const float4* g4 = (const float4*)(G + (size_t)s*1024 + lane*16);
    float4 g0=g4[0], g1=g4[1], g2=g4[2], g3=g4[3];
    const float4* e4 = (const float4*)(ef + (size_t)e*EDGE_IN);
    float4 f0=e4[0], f1=e4[1], f2=e4[2], f3=e4[3];
    float m = P[(size_t)s*H + lane];
    m = fmaf(f0.x,g0.x, fmaf(f0.y,g0.y, fmaf(f0.z,g0.z, fmaf(f0.w,g0.w, m))));
    m = fmaf(f1.x,g1.x, fmaf(f1.y,g1.y, fmaf(f1.z,g1.z, fmaf(f1.w,g1.w, m))));
    m = fmaf(f2.x,g2.x, fmaf(f2.y,g2.y, fmaf(f2.z,g2.z, fmaf(f2.w,g2.w, m))));
    m = fmaf(f3.x,g3.x, fmaf(f3.y,g3.y, fmaf(f3.z,g3.z, fmaf(f3.w,g3.w, m))));
    atomicAdd(&agg[(size_t)d*H + lane], m);
  }
}

// ==================== Bc pack for GRU GEMM ====================
__global__ __launch_bounds__(256) void build_bc(
    const float* __restrict__ Wih, const float* __restrict__ Whh,
    float* __restrict__ Bc){
  int i = blockIdx.x*256 + threadIdx.x;
  int k = i >> 8, c = i & 255;
  float v;
  if (c < 128){
    v = (k < 64) ? Wih[(size_t)c*H + k] : Whh[(size_t)c*H + (k-64)];
  } else if (c < 192){
    int d = c - 128;
    v = (k < 64) ? Wih[(size_t)(128+d)*H + k] : 0.f;
  } else {
    int d = c - 192;
    v = (k < 64) ? 0.f : Whh[(size_t)(128+d)*H + (k-64)];
  }
  Bc[i] = v;
}

// ==================== GRU GEMM ====================
__global__ __launch_bounds__(256) void gru_mm(
    const float* __restrict__ agg, const float* __restrict__ bconv,
    const float* __restrict__ hm, const float* __restrict__ Bc,
    float* __restrict__ C){
  __shared__ float A_s[128][64];
  __shared__ float B_s[32][256];
  int t = threadIdx.x;
  int nb = blockIdx.x * 64;
  #pragma unroll
  for (int p = 0; p < 4; ++p){
    int idx = p*256 + t;
    int n = idx >> 4, k4 = idx & 15;
    float4 v = ((const float4*)(agg + (size_t)(nb+n)*H))[k4];
    float4 b = ((const float4*)bconv)[k4];
    A_s[k4*4+0][n]=fmaxf(v.x+b.x,0.f); A_s[k4*4+1][n]=fmaxf(v.y+b.y,0.f);
    A_s[k4*4+2][n]=fmaxf(v.z+b.z,0.f); A_s[k4*4+3][n]=fmaxf(v.w+b.w,0.f);
    float4 w = ((const float4*)(hm + (size_t)(nb+n)*H))[k4];
    A_s[64+k4*4+0][n]=w.x; A_s[64+k4*4+1][n]=w.y;
    A_s[64+k4*4+2][n]=w.z; A_s[64+k4*4+3][n]=w.w;
  }
  int eg = t & 7, cg = t >> 3;
  float acc[8][8] = {};
  #pragma unroll
  for (int kc = 0; kc < 4; ++kc){
    __syncthreads();
    #pragma unroll
    for (int p = 0; p < 8; ++p){
      int idx = p*256 + t;
      int r = idx >> 6, c4 = idx & 63;
      *(float4*)&B_s[r][c4*4] = ((const float4*)(Bc + (size_t)(kc*32+r)*256))[c4];
    }
    __syncthreads();
    #pragma unroll 2
    for (int r = 0; r < 32; ++r){
      int k = kc*32 + r;
      float4 a0 = *(const float4*)&A_s[k][eg*8];
      float4 a1 = *(const float4*)&A_s[k][eg*8+4];
      float4 b0 = *(const float4*)&B_s[r][cg*8];
      float4 b1 = *(const float4*)&B_s[r][cg*8+4];
      float av[8] = {a0.x,a0.y,a0.z,a0.w,a1.x,a1.y,a1.z,a1.w};
      float bv[8] = {b0.x,b0.y,b0.z,b0.w,b1.x,b1.y,b1.z,b1.w};
      #pragma unroll
      for (int n = 0; n < 8; ++n)
        #pragma unroll
        for (int c = 0; c < 8; ++c) acc[n][c] += av[n]*bv[c];
    }
  }
  #pragma unroll
  for (int n = 0; n < 8; ++n){
    int node = nb + eg*8 + n;
    float* cp = C + (size_t)node*256 + cg*8;
    *(float4*)cp       = make_float4(acc[n][0],acc[n][1],acc[n][2],acc[n][3]);
    *(float4*)(cp + 4) = make_float4(acc[n][4],acc[n][5],acc[n][6],acc[n][7]);
  }
}

// ==================== GRU combine ====================
__global__ __launch_bounds__(256) void gru_combine(
    const float* __restrict__ C, const float* __restrict__ bih,
    const float* __restrict__ bhh, float* __restrict__ h){
  int i = blockIdx.x*256 + threadIdx.x;
  int n = i >> 4, d4 = i & 15;
  float4 c0 = ((const float4*)(C + (size_t)n*256      ))[d4];
  float4 c1 = ((const float4*)(C + (size_t)n*256 +  64))[d4];
  float4 c2 = ((const float4*)(C + (size_t)n*256 + 128))[d4];
  float4 c3 = ((const float4*)(C + (size_t)n*256 + 192))[d4];
  float4 hv = ((const float4*)(h + (size_t)n*H))[d4];
  float4 bi0 = ((const float4*)(bih      ))[d4];
  float4 bh0 = ((const float4*)(bhh      ))[d4];
  float4 bi1 = ((const float4*)(bih +  64))[d4];
  float4 bh1 = ((const float4*)(bhh +  64))[d4];
  float4 bi2 = ((const float4*)(bih + 128))[d4];
  float4 bh2 = ((const float4*)(bhh + 128))[d4];
  float4 o;
  {
    float r = sigmoidf_(c0.x + bi0.x + bh0.x);
    float z = sigmoidf_(c1.x + bi1.x + bh1.x);
    float nn = tanhf(c2.x + bi2.x + r*(c3.x + bh2.x));
    o.x = (1.f - z)*nn + z*hv.x;
  }
  {
    float r = sigmoidf_(c0.y + bi0.y + bh0.y);
    float z = sigmoidf_(c1.y + bi1.y + bh1.y);
    float nn = tanhf(c2.y + bi2.y + r*(c3.y + bh2.y));
    o.y = (1.f - z)*nn + z*hv.y;
  }
  {
    float r = sigmoidf_(c0.z + bi0.z + bh0.z);
    float z = sigmoidf_(c1.z + bi1.z + bh1.z);
    float nn = tanhf(c2.z + bi2.z + r*(c3.z + bh2.z));
    o.z = (1.f - z)*nn + z*hv.z;
  }
  {
    float r = sigmoidf_(c0.w + bi0.w + bh0.w);
    float z = sigmoidf_(c1.w + bi1.w + bh1.w);
    float nn = tanhf(c2.w + bi2.w + r*(c3.w + bh2.w));
    o.w = (1.f - z)*nn + z*hv.w;
  }
  ((float4*)(h + (size_t)n*H))[d4] = o;
}

// ==================== fallback fused edge kernel (tiers B/C) ====================
__global__ __launch_bounds__(256) void edge_msg_kernel(
    const float* __restrict__ x, const float* __restrict__ ef,
    const int* __restrict__ src, const int* __restrict__ dst,
    const float* __restrict__ We, const float* __restrict__ be,
    float* __restrict__ agg){
  __shared__ float x_s[64][H+1];
  __shared__ float w_s[256][20];
  __shared__ float b_s[256];
  __shared__ int src_s[64], dst_s[64];
  int t = threadIdx.x;
  int ebase = blockIdx.x * 64;
  if (t < 64){ src_s[t] = src[ebase + t]; dst_s[t] = dst[ebase + t]; }
  __syncthreads();
  for (int idx = t; idx < 64*H; idx += 256){
    int e = idx >> 6, hh = idx & 63;
    x_s[e][hh] = x[(size_t)src_s[e]*H + hh];
  }
  int eg = t & 15, og = t >> 4;
  float efr[4][16];
  #pragma unroll
  for (int j = 0; j < 4; ++j){
    const float4* p = (const float4*)(ef + (size_t)(ebase + eg*4 + j)*EDGE_IN);
    #pragma unroll
    for (int q = 0; q < 4; ++q){
      float4 v = p[q];
      efr[j][q*4+0]=v.x; efr[j][q*4+1]=v.y; efr[j][q*4+2]=v.z; efr[j][q*4+3]=v.w;
    }
  }
  float acc[4][4] = {};
  for (int ht = 0; ht < 16; ++ht){
    __syncthreads();
    {
      const float4* wp = (const float4*)(We + (size_t)(ht*256 + t)*EDGE_IN);
      float4 a = wp[0], b = wp[1], c = wp[2], d = wp[3];
      float* wr = w_s[t];
      wr[0]=a.x; wr[1]=a.y; wr[2]=a.z; wr[3]=a.w;
      wr[4]=b.x; wr[5]=b.y; wr[6]=b.z; wr[7]=b.w;
      wr[8]=c.x; wr[9]=c.y; wr[10]=c.z; wr[11]=c.w;
      wr[12]=d.x; wr[13]=d.y; wr[14]=d.z; wr[15]=d.w;
      b_s[t] = be[ht*256 + t];
    }
    __syncthreads();
    #pragma unroll
    for (int hl = 0; hl < 4; ++hl){
      int hglob = ht*4 + hl;
      float xv[4];
      #pragma unroll
      for (int j = 0; j < 4; ++j) xv[j] = x_s[eg*4 + j][hglob];
      #pragma unroll
      for (int oo = 0; oo < 4; ++oo){
        int row = hl*64 + og*4 + oo;
        const float4* wp4 = (const float4*)w_s[row];
        float4 w0 = wp4[0], w1 = wp4[1], w2 = wp4[2], w3 = wp4[3];
        float bb = b_s[row];
        #pragma unroll
        for (int j = 0; j < 4; ++j){
          float d = bb;
          d += efr[j][0]*w0.x + efr[j][1]*w0.y + efr[j][2]*w0.z + efr[j][3]*w0.w;
          d += efr[j][4]*w1.x + efr[j][5]*w1.y + efr[j][6]*w1.z + efr[j][7]*w1.w;
          d += efr[j][8]*w2.x + efr[j][9]*w2.y + efr[j][10]*w2.z + efr[j][11]*w2.w;
          d += efr[j][12]*w3.x + efr[j][13]*w3.y + efr[j][14]*w3.z + efr[j][15]*w3.w;
          acc[j][oo] += xv[j]*d;
        }
      }
    }
  }
  #pragma unroll
  for (int j = 0; j < 4; ++j){
    int dn = dst_s[eg*4 + j];
    #pragma unroll
    for (int oo = 0; oo < 4; ++oo)
      atomicAdd(&agg[(size_t)dn*H + og*4 + oo], acc[j][oo]);
  }
}

// ==================== fallback GRU (tier C) ====================
__global__ __launch_bounds__(256) void gru_kernel(
    const float* __restrict__ agg, const float* __restrict__ bconv,
    const float* __restrict__ Wih, const float* __restrict__ Whh,
    const float* __restrict__ bih, const float* __restrict__ bhh,
    float* __restrict__ h){
  __shared__ float a_s[4][H], h_s[4][H];
  int t = threadIdx.x;
  int nb = blockIdx.x * 4;
  int nl = t >> 6, d = t & 63;
  int n = nb + nl;
  float av = fmaxf(agg[(size_t)n*H + d] + bconv[d], 0.0f);
  float hv = h[(size_t)n*H + d];
  a_s[nl][d] = av; h_s[nl][d] = hv;
  __syncthreads();
  const float4* av4 = (const float4*)a_s[nl];
  const float4* hv4 = (const float4*)h_s[nl];
  float gi[3], gh[3];
  #pragma unroll
  for (int g = 0; g < 3; ++g){
    int row = g*64 + d;
    const float4* wi = (const float4*)(Wih + (size_t)row*H);
    const float4* wh = (const float4*)(Whh + (size_t)row*H);
    float si = bih[row], sh = bhh[row];
    #pragma unroll
    for (int k4 = 0; k4 < 16; ++k4){
      float4 w1 = wi[k4], w2 = wh[k4];
      float4 aa = av4[k4], hh = hv4[k4];
      si += aa.x*w1.x + aa.y*w1.y + aa.z*w1.z + aa.w*w1.w;
      sh += hh.x*w2.x + hh.y*w2.y + hh.z*w2.z + hh.w*w2.w;
    }
    gi[g] = si; gh[g] = sh;
  }
  float r = sigmoidf_(gi[0] + gh[0]);
  float z = sigmoidf_(gi[1] + gh[1]);
  float nn = tanhf(gi[2] + r*gh[2]);
  h[(size_t)n*H + d] = (1.0f - z)*nn + z*hv;
}

// ==================== Bl pack for LSTM GEMM: Bl[k][c], k<384, c<512 ====================
// k<256: lWih[c*256+k]; else lWhh[c*128+(k-256)]
__global__ __launch_bounds__(256) void build_bl(
    const float* __restrict__ Wih, const float* __restrict__ Whh,
    float* __restrict__ Bl){
  int i = blockIdx.x*256 + threadIdx.x;   // 196608
  int k = i >> 9, c = i & 511;
  float v = (k < 256) ? Wih[(size_t)c*QS + k] : Whh[(size_t)c*D2 + (k-256)];
  Bl[i] = v;
}

// ==================== LSTM GEMM: gates[256x512] = [qstar|hl] @ Bl ====================
// grid (4, 2): 64 graphs x 256 gate-cols per block, K=384 in 12 chunks of 32
__global__ __launch_bounds__(256) void lstm_mm(
    const float* __restrict__ qstar, const float* __restrict__ hlm,
    const float* __restrict__ Bl, float* __restrict__ gates){
  __shared__ float A_s[32][64];    // [k][m] 8KB
  __shared__ float B_s[32][256];   // [k][c] 32KB
  int t = threadIdx.x;
  int mb = blockIdx.x * 64;
  int cb = blockIdx.y * 256;
  int eg = t & 7, cg = t >> 3;
  float acc[8][8] = {};
  for (int kc = 0; kc < 12; ++kc){
    __syncthreads();
    // stage A chunk: 64m x 32k
    #pragma unroll
    for (int p = 0; p < 2; ++p){
      int idx = p*256 + t;          // [64m][8k4]
      int m = idx >> 3, k4 = idx & 7;
      float4 v;
      if (kc < 8)
        v = ((const float4*)(qstar + (size_t)(mb+m)*QS + kc*32))[k4];
      else
        v = ((const float4*)(hlm + (size_t)(mb+m)*D2 + (kc-8)*32))[k4];
      A_s[k4*4+0][m]=v.x; A_s[k4*4+1][m]=v.y; A_s[k4*4+2][m]=v.z; A_s[k4*4+3][m]=v.w;
    }
    // stage B chunk: 32k x 256c
    #pragma unroll
    for (int p = 0; p < 8; ++p){
      int idx = p*256 + t;
      int r = idx >> 6, c4 = idx & 63;
      *(float4*)&B_s[r][c4*4] = ((const float4*)(Bl + (size_t)(kc*32+r)*512 + cb))[c4];
    }
    __syncthreads();
    #pragma unroll 2
    for (int r = 0; r < 32; ++r){
      float4 a0 = *(const float4*)&A_s[r][eg*8];
      float4 a1 = *(const float4*)&A_s[r][eg*8+4];
      float4 b0 = *(const float4*)&B_s[r][cg*8];
      float4 b1 = *(const float4*)&B_s[r][cg*8+4];
      float av[8] = {a0.x,a0.y,a0.z,a0.w,a1.x,a1.y,a1.z,a1.w};
      float bv[8] = {b0.x,b0.y,b0.z,b0.w,b1.x,b1.y,b1.z,b1.w};
      #pragma unroll
      for (int n = 0; n < 8; ++n)
        #pragma unroll
        for (int c = 0; c < 8; ++c) acc[n][c] += av[n]*bv[c];
    }
  }
  #pragma unroll
  for (int n = 0; n < 8; ++n){
    int g = mb + eg*8 + n;
    float* gp = gates + (size_t)g*512 + cb + cg*8;
    *(float4*)gp       = make_float4(acc[n][0],acc[n][1],acc[n][2],acc[n][3]);
    *(float4*)(gp + 4) = make_float4(acc[n][4],acc[n][5],acc[n][6],acc[n][7]);
  }
}

// ==================== LSTM combine: c/h update ====================
__global__ __launch_bounds__(256) void lstm_combine(
    const float* __restrict__ gates, const float* __restrict__ bih,
    const float* __restrict__ bhh, float* __restrict__ hl, float* __restrict__ cl){
  int i = blockIdx.x*256 + threadIdx.x;   // 32768
  int g = i >> 7, d = i & 127;
  const float* gr = gates + (size_t)g*512;
  float iv = gr[d]       + bih[d]       + bhh[d];
  float fv = gr[128 + d] + bih[128 + d] + bhh[128 + d];
  float gv = gr[256 + d] + bih[256 + d] + bhh[256 + d];
  float ov = gr[384 + d] + bih[384 + d] + bhh[384 + d];
  float c = sigmoidf_(fv)*cl[(size_t)g*D2 + d] + sigmoidf_(iv)*tanhf(gv);
  float hn = sigmoidf_(ov)*tanhf(c);
  cl[(size_t)g*D2 + d] = c;
  hl[(size_t)g*D2 + d] = hn;
}

// ==================== attention + pooling ====================
__global__ __launch_bounds__(256) void attn_kernel(
    const float* __restrict__ x0, const float* __restrict__ h,
    const float* __restrict__ hl, float* __restrict__ qstar){
  __shared__ float q_s[D2];
  __shared__ float red[256];
  __shared__ float alpha_s[160];
  int g = blockIdx.x, t = threadIdx.x;
  int n0 = (g*N_NODES + N_GRAPHS - 1)/N_GRAPHS;
  int n1 = ((g+1)*N_NODES + N_GRAPHS - 1)/N_GRAPHS;
  int cnt = n1 - n0;
  if (t < D2) q_s[t] = hl[(size_t)g*D2 + t];
  __syncthreads();
  float e = -1e30f, exv = 0.0f;
  int n = n0 + t;
  if (t < cnt){
    const float4* xr = (const float4*)(x0 + (size_t)n*H);
    const float4* hr = (const float4*)(h  + (size_t)n*H);
    const float4* q1 = (const float4*)q_s;
    const float4* q2 = (const float4*)(q_s + H);
    float s = 0.0f;
    #pragma unroll
    for (int k4 = 0; k4 < 16; ++k4){
      float4 a = xr[k4], b = q1[k4];
      s += a.x*b.x + a.y*b.y + a.z*b.z + a.w*b.w;
    }
    #pragma unroll
    for (int k4 = 0; k4 < 16; ++k4){
      float4 a = hr[k4], b = q2[k4];
      s += a.x*b.x + a.y*b.y + a.z*b.z + a.w*b.w;
    }
    e = s;
  }
  red[t] = e; __syncthreads();
  for (int off = 128; off >= 1; off >>= 1){
    if (t < off) red[t] = fmaxf(red[t], red[t+off]);
    __syncthreads();
  }
  float m = red[0];
  __syncthreads();
  exv = (t < cnt) ? expf(e - m) : 0.0f;
  red[t] = exv; __syncthreads();
  for (int off = 128; off >= 1; off >>= 1){
    if (t < off) red[t] += red[t+off];
    __syncthreads();
  }
  float denom = red[0];
  __syncthreads();
  if (t < cnt) alpha_s[t] = exv / denom;
  __syncthreads();
  {
    int d = t & 127, half = t >> 7;
    const float* base = (d < H) ? x0 : h;
    int kk = d & 63;
    float acc2 = 0.f;
    for (int i = half; i < cnt; i += 2)
      acc2 += alpha_s[i] * base[(size_t)(n0+i)*H + kk];
    red[t] = acc2;
  }
  __syncthreads();
  if (t < D2){
    float v = red[t] + red[t + 128];
    qstar[(size_t)g*QS + t]      = q_s[t];
    qstar[(size_t)g*QS + D2 + t] = v;
  }
}

// ==================== readout ====================
__global__ __launch_bounds__(256) void out_kernel(
    const float* __restrict__ qstar, const float* __restrict__ Wsp,
    const float* __restrict__ bsp, const float* __restrict__ prelu,
    float* __restrict__ out){
  __shared__ float q_s[QS];
  int g = blockIdx.x & 255;
  int jb = blockIdx.x >> 8;
  int t = threadIdx.x;
  q_s[t] = qstar[(size_t)g*QS + t];
  __syncthreads();
  int j = jb*256 + t;
  const float4* w = (const float4*)(Wsp + (size_t)j*QS);
  const float4* q4 = (const float4*)q_s;
  float acc = bsp[j];
  #pragma unroll
  for (int k4 = 0; k4 < 64; ++k4){
    float4 wv = w[k4]; float4 qv = q4[k4];
    acc += qv.x*wv.x + qv.y*wv.y + qv.z*wv.z + qv.w*wv.w;
  }
  float pw = prelu[0];
  out[(size_t)g*READOUT + j] = (acc >= 0.0f) ? acc : pw*acc;
}

extern "C" void kernel_launch(void* const* d_in, const int* in_sizes, int n_in,
                              void* d_out, int out_size, void* d_ws, size_t ws_size,
                              hipStream_t stream) {
  const float* node_feats = (const float*)d_in[0];
  const float* edge_feats = (const float*)d_in[1];
  const int*   esrc       = (const int*)d_in[2];
  const int*   edst       = (const int*)d_in[3];
  const float* Wproj = (const float*)d_in[5];
  const float* bproj = (const float*)d_in[6];
  const float* Wedge = (const float*)d_in[7];
  const float* bedge = (const float*)d_in[8];
  const float* bconv = (const float*)d_in[9];
  const float* gWih  = (const float*)d_in[10];
  const float* gWhh  = (const float*)d_in[11];
  const float* gbih  = (const float*)d_in[12];
  const float* gbhh  = (const float*)d_in[13];
  const float* lWih  = (const float*)d_in[14];
  const float* lWhh  = (const float*)d_in[15];
  const float* lbih  = (const float*)d_in[16];
  const float* lbhh  = (const float*)d_in[17];
  const float* Wsp   = (const float*)d_in[18];
  const float* bsp   = (const float*)d_in[19];
  const float* prelu = (const float*)d_in[20];

  float* ws    = (float*)d_ws;
  float* x0    = ws;                     // 2,560,000
  float* h     = ws + 2560000;           // 2,560,000
  float* agg   = ws + 5120000;           // 2,560,000
  float* qstar = ws + 7680000;           // 65,536
  float* hl    = qstar + 65536;          // 32,768
  float* cl    = hl + 32768;             // 32,768
  float* Bc    = cl + 32768;             // 32,768   (ends 7,843,840)
  float* P     = Bc + 32768;             // 2,560,000
  float* G     = P + 2560000;            // 40,960,000 (ends 51,363,840)
  // s2s-phase scratch overlaps dead agg region (agg unused after MP loop):
  float* Bl    = agg;                    // 196,608 (768KB)
  float* gatesL= agg + 196608;           // 131,072 (512KB)

  const size_t needA = 51363840ull * sizeof(float);  // ~205.5 MB
  const size_t needB = 18083840ull * sizeof(float);  // ~72.3 MB
  int tier = (ws_size >= needA) ? 0 : ((ws_size >= needB) ? 1 : 2);
  float* C = (tier == 0) ? G : P;

  hipMemsetAsync(qstar, 0, (65536 + 32768 + 32768)*sizeof(float), stream);

  proj_mm<<<N_NODES/64, 256, 0, stream>>>(node_feats, Wproj, bproj, x0, h);

  if (tier <= 1)
    build_bc<<<128, 256, 0, stream>>>(gWih, gWhh, Bc);

  for (int s = 0; s < 3; ++s){
    if (tier == 0){
      g_mm<<<dim3(N_NODES/64, 4), 256, 0, stream>>>(h, Wedge, G);
      p_mm<<<N_NODES/64, 256, 0, stream>>>(h, bedge, P);
      hipMemsetAsync(agg, 0, (size_t)N_NODES*H*sizeof(float), stream);
      edge_apply<<<2500, 256, 0, stream>>>(G, P, edge_feats, esrc, edst, agg);
    } else {
      hipMemsetAsync(agg, 0, (size_t)N_NODES*H*sizeof(float), stream);
      edge_msg_kernel<<<N_EDGES/64, 256, 0, stream>>>(h, edge_feats, esrc, edst, Wedge, bedge, agg);
    }
    if (tier <= 1){
      gru_mm<<<N_NODES/64, 256, 0, stream>>>(agg, bconv, h, Bc, C);
      gru_combine<<<N_NODES*H/4/256, 256, 0, stream>>>(C, gbih, gbhh, h);
    } else {
      gru_kernel<<<N_NODES/4, 256, 0, stream>>>(agg, bconv, gWih, gWhh, gbih, gbhh, h);
    }
  }

  // LSTM weight pack (agg region is dead from here on)
  build_bl<<<768, 256, 0, stream>>>(lWih, lWhh, Bl);

  for (int s = 0; s < 3; ++s){
    lstm_mm<<<dim3(4, 2), 256, 0, stream>>>(qstar, hl, Bl, gatesL);
    lstm_combine<<<128, 256, 0, stream>>>(gatesL, lbih, lbhh, hl, cl);
    attn_kernel<<<N_GRAPHS, 256, 0, stream>>>(x0, h, hl, qstar);
  }

  out_kernel<<<4*N_GRAPHS, 256, 0, stream>>>(qstar, Wsp, bsp, prelu, (float*)d_out);
}

// Round 4
// 885.970 us; speedup vs baseline: 3.6048x; 1.0633x over previous
//
#include <hip/hip_runtime.h>
#include <math.h>

#define H 64
#define NODE_IN 128
#define EDGE_IN 16
#define N_NODES 40000
#define N_EDGES 80000
#define N_GRAPHS 256
#define READOUT 1024
#define D2 128   // 2H
#define QS 256   // 4H

__device__ __forceinline__ float sigmoidf_(float x){ return 1.0f/(1.0f + expf(-x)); }

// A_s staging uses an XOR granule swizzle: element (k,n) lives at float index
// ( ((n>>2) ^ ((k>>2)&15)) * 4 + (n&3) ) within row k. Writes (16 lanes share n,
// k4 varies) hit 16 distinct granules -> conflict-free; float4 reads of logical
// granules {2eg, 2eg+1} land on phys {p0, p0^1}, both 16B-aligned, <=2-way banks.

// ==================== proj GEMM: x0 = relu(nf @ Wp^T + bp); h = x0 ====================
__global__ __launch_bounds__(256) void proj_mm(
    const float* __restrict__ nf, const float* __restrict__ Wp,
    const float* __restrict__ bp, float* __restrict__ x0, float* __restrict__ h){
  __shared__ float A_s[NODE_IN][64];
  __shared__ float B_s[NODE_IN][64];
  int t = threadIdx.x;
  int nb = blockIdx.x * 64;
  #pragma unroll
  for (int p = 0; p < 8; ++p){
    int idx = p*256 + t;
    int n = idx >> 5, k4 = idx & 31;
    float4 v = ((const float4*)(nf + (size_t)(nb+n)*NODE_IN))[k4];
    int base = (((n>>2) ^ (k4 & 15)) << 2) + (n & 3);
    A_s[k4*4+0][base]=v.x; A_s[k4*4+1][base]=v.y;
    A_s[k4*4+2][base]=v.z; A_s[k4*4+3][base]=v.w;
  }
  #pragma unroll
  for (int p = 0; p < 8; ++p){
    int idx = p*256 + t;
    int c = idx & 63, k4 = idx >> 6;
    float4 v = ((const float4*)(Wp + (size_t)c*NODE_IN))[k4];
    B_s[k4*4+0][c]=v.x; B_s[k4*4+1][c]=v.y; B_s[k4*4+2][c]=v.z; B_s[k4*4+3][c]=v.w;
  }
  __syncthreads();
  int eg = t & 15, cg = t >> 4;
  float acc[4][4] = {};
  #pragma unroll 4
  for (int k = 0; k < NODE_IN; ++k){
    int s = (k >> 2) & 15;
    float4 a = *(const float4*)&A_s[k][(eg ^ s) << 2];
    float4 b = *(const float4*)&B_s[k][cg*4];
    float av[4] = {a.x,a.y,a.z,a.w};
    float bv[4] = {b.x,b.y,b.z,b.w};
    #pragma unroll
    for (int j = 0; j < 4; ++j)
      #pragma unroll
      for (int c = 0; c < 4; ++c) acc[j][c] += av[j]*bv[c];
  }
  float4 bb = ((const float4*)bp)[cg];
  float bv[4] = {bb.x,bb.y,bb.z,bb.w};
  #pragma unroll
  for (int j = 0; j < 4; ++j){
    int n = nb + eg*4 + j;
    float4 o;
    o.x = fmaxf(acc[j][0]+bv[0], 0.f);
    o.y = fmaxf(acc[j][1]+bv[1], 0.f);
    o.z = fmaxf(acc[j][2]+bv[2], 0.f);
    o.w = fmaxf(acc[j][3]+bv[3], 0.f);
    *(float4*)(x0 + (size_t)n*H + cg*4) = o;
    *(float4*)(h  + (size_t)n*H + cg*4) = o;
  }
}

// ==================== G GEMM: G[40000x1024] = x @ We_view[64][1024] ====================
// grid (625,4); tile 64n x 256c, K=64 in 4 chunks of 16; LDS 32KB -> 5 blocks/CU
__global__ __launch_bounds__(256) void g_mm(
    const float* __restrict__ x, const float* __restrict__ We,
    float* __restrict__ G){
  __shared__ float A_s[64][64];    // swizzled, 16KB
  __shared__ float B_s[16][256];   // 16KB
  int t = threadIdx.x;
  int nb = blockIdx.x * 64;
  int cb = blockIdx.y * 256;
  #pragma unroll
  for (int p = 0; p < 4; ++p){
    int idx = p*256 + t;
    int n = idx >> 4, k4 = idx & 15;
    float4 v = ((const float4*)(x + (size_t)(nb+n)*H))[k4];
    int base = (((n>>2) ^ k4) << 2) + (n & 3);
    A_s[k4*4+0][base]=v.x; A_s[k4*4+1][base]=v.y;
    A_s[k4*4+2][base]=v.z; A_s[k4*4+3][base]=v.w;
  }
  int eg = t & 7, cg = t >> 3;
  float acc[8][8] = {};
  #pragma unroll
  for (int kc = 0; kc < 4; ++kc){
    __syncthreads();
    #pragma unroll
    for (int p = 0; p < 4; ++p){
      int idx = p*256 + t;
      int r = idx >> 6, c4 = idx & 63;
      *(float4*)&B_s[r][c4*4] = ((const float4*)(We + (size_t)(kc*16+r)*1024 + cb))[c4];
    }
    __syncthreads();
    #pragma unroll 2
    for (int r = 0; r < 16; ++r){
      int k = kc*16 + r;
      int p0 = (eg*2) ^ ((k >> 2) & 15);
      float4 a0 = *(const float4*)&A_s[k][p0 << 2];
      float4 a1 = *(const float4*)&A_s[k][(p0 ^ 1) << 2];
      float4 b0 = *(const float4*)&B_s[r][cg*8];
      float4 b1 = *(const float4*)&B_s[r][cg*8+4];
      float av[8] = {a0.x,a0.y,a0.z,a0.w,a1.x,a1.y,a1.z,a1.w};
      float bv[8] = {b0.x,b0.y,b0.z,b0.w,b1.x,b1.y,b1.z,b1.w};
      #pragma unroll
      for (int n = 0; n < 8; ++n)
        #pragma unroll
        for (int c = 0; c < 8; ++c) acc[n][c] += av[n]*bv[c];
    }
  }
  #pragma unroll
  for (int n = 0; n < 8; ++n){
    int node = nb + eg*8 + n;
    float* gp = G + (size_t)node*1024 + cb + cg*8;
    *(float4*)gp       = make_float4(acc[n][0],acc[n][1],acc[n][2],acc[n][3]);
    *(float4*)(gp + 4) = make_float4(acc[n][4],acc[n][5],acc[n][6],acc[n][7]);
  }
}

// ==================== P GEMM: P[40000x64] = x @ Bb ====================
__global__ __launch_bounds__(256) void p_mm(
    const float* __restrict__ x, const float* __restrict__ be, float* __restrict__ P){
  __shared__ float A_s[64][64];
  __shared__ float B_s[64][64];
  int t = threadIdx.x;
  int nb = blockIdx.x * 64;
  #pragma unroll
  for (int p = 0; p < 4; ++p){
    int idx = p*256 + t;
    int n = idx >> 4, k4 = idx & 15;
    float4 v = ((const float4*)(x + (size_t)(nb+n)*H))[k4];
    int base = (((n>>2) ^ k4) << 2) + (n & 3);
    A_s[k4*4+0][base]=v.x; A_s[k4*4+1][base]=v.y;
    A_s[k4*4+2][base]=v.z; A_s[k4*4+3][base]=v.w;
  }
  #pragma unroll
  for (int p = 0; p < 4; ++p){
    int idx = p*256 + t;
    int r = idx >> 4, c4 = idx & 15;
    *(float4*)&B_s[r][c4*4] = ((const float4*)(be + (size_t)r*64))[c4];
  }
  __syncthreads();
  int eg = t & 15, cg = t >> 4;
  float acc[4][4] = {};
  #pragma unroll 4
  for (int k = 0; k < 64; ++k){
    int s = (k >> 2) & 15;
    float4 a = *(const float4*)&A_s[k][(eg ^ s) << 2];
    float4 b = *(const float4*)&B_s[k][cg*4];
    float av[4] = {a.x,a.y,a.z,a.w};
    float bv[4] = {b.x,b.y,b.z,b.w};
    #pragma unroll
    for (int j = 0; j < 4; ++j)
      #pragma unroll
      for (int c = 0; c < 4; ++c) acc[j][c] += av[j]*bv[c];
  }
  #pragma unroll
  for (int j = 0; j < 4; ++j){
    int n = nb + eg*4 + j;
    *(float4*)(P + (size_t)n*H + cg*4) =
      make_float4(acc[j][0],acc[j][1],acc[j][2],acc[j][3]);
  }
}

// ==================== edge apply ====================
__global__ __launch_bounds__(256) void edge_apply(
    const float* __restrict__ G, const float* __restrict__ P,
    const float* __restrict__ ef, const int* __restrict__ src,
    const int* __restrict__ dst, float* __restrict__ agg){
  int lane = threadIdx.x & 63;
  int wid = blockIdx.x * 4 + (threadIdx.x >> 6);
  int nw = gridDim.x * 4;
  for (int e = wid; e < N_EDGES; e += nw){
    int s = src[e], d = dst[e];
    const float4* g4 = (const float4*)(G + (size_t)s*1024 + lane*16);
    float4 g0=g4[0], g1=g4[1], g2=g4[2], g3=g4[3];
    const float4* e4 = (const float4*)(ef + (size_t)e*EDGE_IN);
    float4 f0=e4[0], f1=e4[1], f2=e4[2], f3=e4[3];
    float m = P[(size_t)s*H + lane];
    m = fmaf(f0.x,g0.x, fmaf(f0.y,g0.y, fmaf(f0.z,g0.z, fmaf(f0.w,g0.w, m))));
    m = fmaf(f1.x,g1.x, fmaf(f1.y,g1.y, fmaf(f1.z,g1.z, fmaf(f1.w,g1.w, m))));
    m = fmaf(f2.x,g2.x, fmaf(f2.y,g2.y, fmaf(f2.z,g2.z, fmaf(f2.w,g2.w, m))));
    m = fmaf(f3.x,g3.x, fmaf(f3.y,g3.y, fmaf(f3.z,g3.z, fmaf(f3.w,g3.w, m))));
    atomicAdd(&agg[(size_t)d*H + lane], m);
  }
}

// ==================== Bc pack for GRU GEMM ====================
__global__ __launch_bounds__(256) void build_bc(
    const float* __restrict__ Wih, const float* __restrict__ Whh,
    float* __restrict__ Bc){
  int i = blockIdx.x*256 + threadIdx.x;
  int k = i >> 8, c = i & 255;
  float v;
  if (c < 128){
    v = (k < 64) ? Wih[(size_t)c*H + k] : Whh[(size_t)c*H + (k-64)];
  } else if (c < 192){
    int d = c - 128;
    v = (k < 64) ? Wih[(size_t)(128+d)*H + k] : 0.f;
  } else {
    int d = c - 192;
    v = (k < 64) ? 0.f : Whh[(size_t)(128+d)*H + (k-64)];
  }
  Bc[i] = v;
}

// ==================== GRU GEMM: C[40000x256] = [relu(agg+bconv)|h] @ Bc ====================
// K=128 in 8 chunks of 16; LDS 48KB -> 3 blocks/CU
__global__ __launch_bounds__(256) void gru_mm(
    const float* __restrict__ agg, const float* __restrict__ bconv,
    const float* __restrict__ hm, const float* __restrict__ Bc,
    float* __restrict__ C){
  __shared__ float A_s[128][64];   // swizzled, 32KB
  __shared__ float B_s[16][256];   // 16KB
  int t = threadIdx.x;
  int nb = blockIdx.x * 64;
  #pragma unroll
  for (int p = 0; p < 4; ++p){
    int idx = p*256 + t;
    int n = idx >> 4, k4 = idx & 15;
    int base = (((n>>2) ^ k4) << 2) + (n & 3);
    float4 v = ((const float4*)(agg + (size_t)(nb+n)*H))[k4];
    float4 b = ((const float4*)bconv)[k4];
    A_s[k4*4+0][base]=fmaxf(v.x+b.x,0.f); A_s[k4*4+1][base]=fmaxf(v.y+b.y,0.f);
    A_s[k4*4+2][base]=fmaxf(v.z+b.z,0.f); A_s[k4*4+3][base]=fmaxf(v.w+b.w,0.f);
    float4 w = ((const float4*)(hm + (size_t)(nb+n)*H))[k4];
    // rows 64+k: (k>>2)&15 = (16+k4)&15 = k4 -> same swizzle base
    A_s[64+k4*4+0][base]=w.x; A_s[64+k4*4+1][base]=w.y;
    A_s[64+k4*4+2][base]=w.z; A_s[64+k4*4+3][base]=w.w;
  }
  int eg = t & 7, cg = t >> 3;
  float acc[8][8] = {};
  #pragma unroll
  for (int kc = 0; kc < 8; ++kc){
    __syncthreads();
    #pragma unroll
    for (int p = 0; p < 4; ++p){
      int idx = p*256 + t;
      int r = idx >> 6, c4 = idx & 63;
      *(float4*)&B_s[r][c4*4] = ((const float4*)(Bc + (size_t)(kc*16+r)*256))[c4];
    }
    __syncthreads();
    #pragma unroll 2
    for (int r = 0; r < 16; ++r){
      int k = kc*16 + r;
      int p0 = (eg*2) ^ ((k >> 2) & 15);
      float4 a0 = *(const float4*)&A_s[k][p0 << 2];
      float4 a1 = *(const float4*)&A_s[k][(p0 ^ 1) << 2];
      float4 b0 = *(const float4*)&B_s[r][cg*8];
      float4 b1 = *(const float4*)&B_s[r][cg*8+4];
      float av[8] = {a0.x,a0.y,a0.z,a0.w,a1.x,a1.y,a1.z,a1.w};
      float bv[8] = {b0.x,b0.y,b0.z,b0.w,b1.x,b1.y,b1.z,b1.w};
      #pragma unroll
      for (int n = 0; n < 8; ++n)
        #pragma unroll
        for (int c = 0; c < 8; ++c) acc[n][c] += av[n]*bv[c];
    }
  }
  #pragma unroll
  for (int n = 0; n < 8; ++n){
    int node = nb + eg*8 + n;
    float* cp = C + (size_t)node*256 + cg*8;
    *(float4*)cp       = make_float4(acc[n][0],acc[n][1],acc[n][2],acc[n][3]);
    *(float4*)(cp + 4) = make_float4(acc[n][4],acc[n][5],acc[n][6],acc[n][7]);
  }
}

// ==================== GRU combine ====================
__global__ __launch_bounds__(256) void gru_combine(
    const float* __restrict__ C, const float* __restrict__ bih,
    const float* __restrict__ bhh, float* __restrict__ h){
  int i = blockIdx.x*256 + threadIdx.x;
  int n = i >> 4, d4 = i & 15;
  float4 c0 = ((const float4*)(C + (size_t)n*256      ))[d4];
  float4 c1 = ((const float4*)(C + (size_t)n*256 +  64))[d4];
  float4 c2 = ((const float4*)(C + (size_t)n*256 + 128))[d4];
  float4 c3 = ((const float4*)(C + (size_t)n*256 + 192))[d4];
  float4 hv = ((const float4*)(h + (size_t)n*H))[d4];
  float4 bi0 = ((const float4*)(bih      ))[d4];
  float4 bh0 = ((const float4*)(bhh      ))[d4];
  float4 bi1 = ((const float4*)(bih +  64))[d4];
  float4 bh1 = ((const float4*)(bhh +  64))[d4];
  float4 bi2 = ((const float4*)(bih + 128))[d4];
  float4 bh2 = ((const float4*)(bhh + 128))[d4];
  float4 o;
  {
    float r = sigmoidf_(c0.x + bi0.x + bh0.x);
    float z = sigmoidf_(c1.x + bi1.x + bh1.x);
    float nn = tanhf(c2.x + bi2.x + r*(c3.x + bh2.x));
    o.x = (1.f - z)*nn + z*hv.x;
  }
  {
    float r = sigmoidf_(c0.y + bi0.y + bh0.y);
    float z = sigmoidf_(c1.y + bi1.y + bh1.y);
    float nn = tanhf(c2.y + bi2.y + r*(c3.y + bh2.y));
    o.y = (1.f - z)*nn + z*hv.y;
  }
  {
    float r = sigmoidf_(c0.z + bi0.z + bh0.z);
    float z = sigmoidf_(c1.z + bi1.z + bh1.z);
    float nn = tanhf(c2.z + bi2.z + r*(c3.z + bh2.z));
    o.z = (1.f - z)*nn + z*hv.z;
  }
  {
    float r = sigmoidf_(c0.w + bi0.w + bh0.w);
    float z = sigmoidf_(c1.w + bi1.w + bh1.w);
    float nn = tanhf(c2.w + bi2.w + r*(c3.w + bh2.w));
    o.w = (1.f - z)*nn + z*hv.w;
  }
  ((float4*)(h + (size_t)n*H))[d4] = o;
}

// ==================== fallback fused edge kernel (tiers B/C) ====================
__global__ __launch_bounds__(256) void edge_msg_kernel(
    const float* __restrict__ x, const float* __restrict__ ef,
    const int* __restrict__ src, const int* __restrict__ dst,
    const float* __restrict__ We, const float* __restrict__ be,
    float* __restrict__ agg){
  __shared__ float x_s[64][H+1];
  __shared__ float w_s[256][20];
  __shared__ float b_s[256];
  __shared__ int src_s[64], dst_s[64];
  int t = threadIdx.x;
  int ebase = blockIdx.x * 64;
  if (t < 64){ src_s[t] = src[ebase + t]; dst_s[t] = dst[ebase + t]; }
  __syncthreads();
  for (int idx = t; idx < 64*H; idx += 256){
    int e = idx >> 6, hh = idx & 63;
    x_s[e][hh] = x[(size_t)src_s[e]*H + hh];
  }
  int eg = t & 15, og = t >> 4;
  float efr[4][16];
  #pragma unroll
  for (int j = 0; j < 4; ++j){
    const float4* p = (const float4*)(ef + (size_t)(ebase + eg*4 + j)*EDGE_IN);
    #pragma unroll
    for (int q = 0; q < 4; ++q){
      float4 v = p[q];
      efr[j][q*4+0]=v.x; efr[j][q*4+1]=v.y; efr[j][q*4+2]=v.z; efr[j][q*4+3]=v.w;
    }
  }
  float acc[4][4] = {};
  for (int ht = 0; ht < 16; ++ht){
    __syncthreads();
    {
      const float4* wp = (const float4*)(We + (size_t)(ht*256 + t)*EDGE_IN);
      float4 a = wp[0], b = wp[1], c = wp[2], d = wp[3];
      float* wr = w_s[t];
      wr[0]=a.x; wr[1]=a.y; wr[2]=a.z; wr[3]=a.w;
      wr[4]=b.x; wr[5]=b.y; wr[6]=b.z; wr[7]=b.w;
      wr[8]=c.x; wr[9]=c.y; wr[10]=c.z; wr[11]=c.w;
      wr[12]=d.x; wr[13]=d.y; wr[14]=d.z; wr[15]=d.w;
      b_s[t] = be[ht*256 + t];
    }
    __syncthreads();
    #pragma unroll
    for (int hl = 0; hl < 4; ++hl){
      int hglob = ht*4 + hl;
      float xv[4];
      #pragma unroll
      for (int j = 0; j < 4; ++j) xv[j] = x_s[eg*4 + j][hglob];
      #pragma unroll
      for (int oo = 0; oo < 4; ++oo){
        int row = hl*64 + og*4 + oo;
        const float4* wp4 = (const float4*)w_s[row];
        float4 w0 = wp4[0], w1 = wp4[1], w2 = wp4[2], w3 = wp4[3];
        float bb = b_s[row];
        #pragma unroll
        for (int j = 0; j < 4; ++j){
          float d = bb;
          d += efr[j][0]*w0.x + efr[j][1]*w0.y + efr[j][2]*w0.z + efr[j][3]*w0.w;
          d += efr[j][4]*w1.x + efr[j][5]*w1.y + efr[j][6]*w1.z + efr[j][7]*w1.w;
          d += efr[j][8]*w2.x + efr[j][9]*w2.y + efr[j][10]*w2.z + efr[j][11]*w2.w;
          d += efr[j][12]*w3.x + efr[j][13]*w3.y + efr[j][14]*w3.z + efr[j][15]*w3.w;
          acc[j][oo] += xv[j]*d;
        }
      }
    }
  }
  #pragma unroll
  for (int j = 0; j < 4; ++j){
    int dn = dst_s[eg*4 + j];
    #pragma unroll
    for (int oo = 0; oo < 4; ++oo)
      atomicAdd(&agg[(size_t)dn*H + og*4 + oo], acc[j][oo]);
  }
}

// ==================== fallback GRU (tier C) ====================
__global__ __launch_bounds__(256) void gru_kernel(
    const float* __restrict__ agg, const float* __restrict__ bconv,
    const float* __restrict__ Wih, const float* __restrict__ Whh,
    const float* __restrict__ bih, const float* __restrict__ bhh,
    float* __restrict__ h){
  __shared__ float a_s[4][H], h_s[4][H];
  int t = threadIdx.x;
  int nb = blockIdx.x * 4;
  int nl = t >> 6, d = t & 63;
  int n = nb + nl;
  float av = fmaxf(agg[(size_t)n*H + d] + bconv[d], 0.0f);
  float hv = h[(size_t)n*H + d];
  a_s[nl][d] = av; h_s[nl][d] = hv;
  __syncthreads();
  const float4* av4 = (const float4*)a_s[nl];
  const float4* hv4 = (const float4*)h_s[nl];
  float gi[3], gh[3];
  #pragma unroll
  for (int g = 0; g < 3; ++g){
    int row = g*64 + d;
    const float4* wi = (const float4*)(Wih + (size_t)row*H);
    const float4* wh = (const float4*)(Whh + (size_t)row*H);
    float si = bih[row], sh = bhh[row];
    #pragma unroll
    for (int k4 = 0; k4 < 16; ++k4){
      float4 w1 = wi[k4], w2 = wh[k4];
      float4 aa = av4[k4], hh = hv4[k4];
      si += aa.x*w1.x + aa.y*w1.y + aa.z*w1.z + aa.w*w1.w;
      sh += hh.x*w2.x + hh.y*w2.y + hh.z*w2.z + hh.w*w2.w;
    }
    gi[g] = si; gh[g] = sh;
  }
  float r = sigmoidf_(gi[0] + gh[0]);
  float z = sigmoidf_(gi[1] + gh[1]);
  float nn = tanhf(gi[2] + r*gh[2]);
  h[(size_t)n*H + d] = (1.0f - z)*nn + z*hv;
}

// ==================== Bl pack for LSTM GEMM ====================
__global__ __launch_bounds__(256) void build_bl(
    const float* __restrict__ Wih, const float* __restrict__ Whh,
    float* __restrict__ Bl){
  int i = blockIdx.x*256 + threadIdx.x;   // 196608
  int k = i >> 9, c = i & 511;
  float v = (k < 256) ? Wih[(size_t)c*QS + k] : Whh[(size_t)c*D2 + (k-256)];
  Bl[i] = v;
}

// ==================== LSTM GEMM: gates[256x512] = [qstar|hl] @ Bl ====================
__global__ __launch_bounds__(256) void lstm_mm(
    const float* __restrict__ qstar, const float* __restrict__ hlm,
    const float* __restrict__ Bl, float* __restrict__ gates){
  __shared__ float A_s[32][64];
  __shared__ float B_s[32][256];
  int t = threadIdx.x;
  int mb = blockIdx.x * 64;
  int cb = blockIdx.y * 256;
  int eg = t & 7, cg = t >> 3;
  float acc[8][8] = {};
  for (int kc = 0; kc < 12; ++kc){
    __syncthreads();
    #pragma unroll
    for (int p = 0; p < 2; ++p){
      int idx = p*256 + t;
      int m = idx >> 3, k4 = idx & 7;
      float4 v;
      if (kc < 8)
        v = ((const float4*)(qstar + (size_t)(mb+m)*QS + kc*32))[k4];
      else
        v = ((const float4*)(hlm + (size_t)(mb+m)*D2 + (kc-8)*32))[k4];
      A_s[k4*4+0][m]=v.x; A_s[k4*4+1][m]=v.y; A_s[k4*4+2][m]=v.z; A_s[k4*4+3][m]=v.w;
    }
    #pragma unroll
    for (int p = 0; p < 8; ++p){
      int idx = p*256 + t;
      int r = idx >> 6, c4 = idx & 63;
      *(float4*)&B_s[r][c4*4] = ((const float4*)(Bl + (size_t)(kc*32+r)*512 + cb))[c4];
    }
    __syncthreads();
    #pragma unroll 2
    for (int r = 0; r < 32; ++r){
      float4 a0 = *(const float4*)&A_s[r][eg*8];
      float4 a1 = *(const float4*)&A_s[r][eg*8+4];
      float4 b0 = *(const float4*)&B_s[r][cg*8];
      float4 b1 = *(const float4*)&B_s[r][cg*8+4];
      float av[8] = {a0.x,a0.y,a0.z,a0.w,a1.x,a1.y,a1.z,a1.w};
      float bv[8] = {b0.x,b0.y,b0.z,b0.w,b1.x,b1.y,b1.z,b1.w};
      #pragma unroll
      for (int n = 0; n < 8; ++n)
        #pragma unroll
        for (int c = 0; c < 8; ++c) acc[n][c] += av[n]*bv[c];
    }
  }
  #pragma unroll
  for (int n = 0; n < 8; ++n){
    int g = mb + eg*8 + n;
    float* gp = gates + (size_t)g*512 + cb + cg*8;
    *(float4*)gp       = make_float4(acc[n][0],acc[n][1],acc[n][2],acc[n][3]);
    *(float4*)(gp + 4) = make_float4(acc[n][4],acc[n][5],acc[n][6],acc[n][7]);
  }
}

// ==================== LSTM combine ====================
__global__ __launch_bounds__(256) void lstm_combine(
    const float* __restrict__ gates, const float* __restrict__ bih,
    const float* __restrict__ bhh, float* __restrict__ hl, float* __restrict__ cl){
  int i = blockIdx.x*256 + threadIdx.x;   // 32768
  int g = i >> 7, d = i & 127;
  const float* gr = gates + (size_t)g*512;
  float iv = gr[d]       + bih[d]       + bhh[d];
  float fv = gr[128 + d] + bih[128 + d] + bhh[128 + d];
  float gv = gr[256 + d] + bih[256 + d] + bhh[256 + d];
  float ov = gr[384 + d] + bih[384 + d] + bhh[384 + d];
  float c = sigmoidf_(fv)*cl[(size_t)g*D2 + d] + sigmoidf_(iv)*tanhf(gv);
  float hn = sigmoidf_(ov)*tanhf(c);
  cl[(size_t)g*D2 + d] = c;
  hl[(size_t)g*D2 + d] = hn;
}

// ==================== attention + pooling (512 threads = 8 waves) ====================
__global__ __launch_bounds__(512) void attn_kernel(
    const float* __restrict__ x0, const float* __restrict__ h,
    const float* __restrict__ hl, float* __restrict__ qstar){
  __shared__ float q_s[D2];
  __shared__ float alpha_s[160];
  __shared__ float wred[8];
  __shared__ float part[8][D2];
  int g = blockIdx.x, t = threadIdx.x;
  int lane = t & 63, w = t >> 6;
  int n0 = (g*N_NODES + N_GRAPHS - 1)/N_GRAPHS;
  int n1 = ((g+1)*N_NODES + N_GRAPHS - 1)/N_GRAPHS;
  int cnt = n1 - n0;
  if (t < D2) q_s[t] = hl[(size_t)g*D2 + t];
  __syncthreads();
  float e = -1e30f;
  if (t < cnt){
    int n = n0 + t;
    const float4* xr = (const float4*)(x0 + (size_t)n*H);
    const float4* hr = (const float4*)(h  + (size_t)n*H);
    const float4* q1 = (const float4*)q_s;
    const float4* q2 = (const float4*)(q_s + H);
    float s = 0.0f;
    #pragma unroll
    for (int k4 = 0; k4 < 16; ++k4){
      float4 a = xr[k4], b = q1[k4];
      s += a.x*b.x + a.y*b.y + a.z*b.z + a.w*b.w;
    }
    #pragma unroll
    for (int k4 = 0; k4 < 16; ++k4){
      float4 a = hr[k4], b = q2[k4];
      s += a.x*b.x + a.y*b.y + a.z*b.z + a.w*b.w;
    }
    e = s;
  }
  // block max via wave shuffles + LDS
  float m = e;
  #pragma unroll
  for (int off = 32; off >= 1; off >>= 1) m = fmaxf(m, __shfl_xor(m, off));
  if (lane == 0) wred[w] = m;
  __syncthreads();
  float gm = wred[0];
  #pragma unroll
  for (int i = 1; i < 8; ++i) gm = fmaxf(gm, wred[i]);
  __syncthreads();
  float ex = (t < cnt) ? expf(e - gm) : 0.0f;
  float sm = ex;
  #pragma unroll
  for (int off = 32; off >= 1; off >>= 1) sm += __shfl_xor(sm, off);
  if (lane == 0) wred[w] = sm;
  __syncthreads();
  float denom = wred[0]+wred[1]+wred[2]+wred[3]+wred[4]+wred[5]+wred[6]+wred[7];
  if (t < cnt) alpha_s[t] = ex / denom;
  __syncthreads();
  // pooling: wave w strides nodes; lane owns dims (lane) of x0 and h
  float acc0 = 0.f, acc1 = 0.f;
  for (int i = w; i < cnt; i += 8){
    float a = alpha_s[i];
    acc0 += a * x0[(size_t)(n0+i)*H + lane];
    acc1 += a * h [(size_t)(n0+i)*H + lane];
  }
  part[w][lane]      = acc0;
  part[w][64 + lane] = acc1;
  __syncthreads();
  if (t < D2){
    float v = 0.f;
    #pragma unroll
    for (int i = 0; i < 8; ++i) v += part[i][t];
    qstar[(size_t)g*QS + t]      = q_s[t];
    qstar[(size_t)g*QS + D2 + t] = v;
  }
}

// ==================== readout ====================
__global__ __launch_bounds__(256) void out_kernel(
    const float* __restrict__ qstar, const float* __restrict__ Wsp,
    const float* __restrict__ bsp, const float* __restrict__ prelu,
    float* __restrict__ out){
  __shared__ float q_s[QS];
  int g = blockIdx.x & 255;
  int jb = blockIdx.x >> 8;
  int t = threadIdx.x;
  q_s[t] = qstar[(size_t)g*QS + t];
  __syncthreads();
  int j = jb*256 + t;
  const float4* w = (const float4*)(Wsp + (size_t)j*QS);
  const float4* q4 = (const float4*)q_s;
  float acc = bsp[j];
  #pragma unroll
  for (int k4 = 0; k4 < 64; ++k4){
    float4 wv = w[k4]; float4 qv = q4[k4];
    acc += qv.x*wv.x + qv.y*wv.y + qv.z*wv.z + qv.w*wv.w;
  }
  float pw = prelu[0];
  out[(size_t)g*READOUT + j] = (acc >= 0.0f) ? acc : pw*acc;
}

extern "C" void kernel_launch(void* const* d_in, const int* in_sizes, int n_in,
                              void* d_out, int out_size, void* d_ws, size_t ws_size,
                              hipStream_t stream) {
  const float* node_feats = (const float*)d_in[0];
  const float* edge_feats = (const float*)d_in[1];
  const int*   esrc       = (const int*)d_in[2];
  const int*   edst       = (const int*)d_in[3];
  const float* Wproj = (const float*)d_in[5];
  const float* bproj = (const float*)d_in[6];
  const float* Wedge = (const float*)d_in[7];
  const float* bedge = (const float*)d_in[8];
  const float* bconv = (const float*)d_in[9];
  const float* gWih  = (const float*)d_in[10];
  const float* gWhh  = (const float*)d_in[11];
  const float* gbih  = (const float*)d_in[12];
  const float* gbhh  = (const float*)d_in[13];
  const float* lWih  = (const float*)d_in[14];
  const float* lWhh  = (const float*)d_in[15];
  const float* lbih  = (const float*)d_in[16];
  const float* lbhh  = (const float*)d_in[17];
  const float* Wsp   = (const float*)d_in[18];
  const float* bsp   = (const float*)d_in[19];
  const float* prelu = (const float*)d_in[20];

  float* ws    = (float*)d_ws;
  float* x0    = ws;                     // 2,560,000
  float* h     = ws + 2560000;           // 2,560,000
  float* agg   = ws + 5120000;           // 2,560,000
  float* qstar = ws + 7680000;           // 65,536
  float* hl    = qstar + 65536;          // 32,768
  float* cl    = hl + 32768;             // 32,768
  float* Bc    = cl + 32768;             // 32,768   (ends 7,843,840)
  float* P     = Bc + 32768;             // 2,560,000
  float* G     = P + 2560000;            // 40,960,000 (ends 51,363,840)
  float* Bl    = agg;                    // s2s phase reuses dead agg
  float* gatesL= agg + 196608;

  const size_t needA = 51363840ull * sizeof(float);  // ~205.5 MB
  const size_t needB = 18083840ull * sizeof(float);  // ~72.3 MB
  int tier = (ws_size >= needA) ? 0 : ((ws_size >= needB) ? 1 : 2);
  float* C = (tier == 0) ? G : P;

  hipMemsetAsync(qstar, 0, (65536 + 32768 + 32768)*sizeof(float), stream);

  proj_mm<<<N_NODES/64, 256, 0, stream>>>(node_feats, Wproj, bproj, x0, h);

  if (tier <= 1)
    build_bc<<<128, 256, 0, stream>>>(gWih, gWhh, Bc);

  for (int s = 0; s < 3; ++s){
    if (tier == 0){
      g_mm<<<dim3(N_NODES/64, 4), 256, 0, stream>>>(h, Wedge, G);
      p_mm<<<N_NODES/64, 256, 0, stream>>>(h, bedge, P);
      hipMemsetAsync(agg, 0, (size_t)N_NODES*H*sizeof(float), stream);
      edge_apply<<<2500, 256, 0, stream>>>(G, P, edge_feats, esrc, edst, agg);
    } else {
      hipMemsetAsync(agg, 0, (size_t)N_NODES*H*sizeof(float), stream);
      edge_msg_kernel<<<N_EDGES/64, 256, 0, stream>>>(h, edge_feats, esrc, edst, Wedge, bedge, agg);
    }
    if (tier <= 1){
      gru_mm<<<N_NODES/64, 256, 0, stream>>>(agg, bconv, h, Bc, C);
      gru_combine<<<N_NODES*H/4/256, 256, 0, stream>>>(C, gbih, gbhh, h);
    } else {
      gru_kernel<<<N_NODES/4, 256, 0, stream>>>(agg, bconv, gWih, gWhh, gbih, gbhh, h);
    }
  }

  build_bl<<<768, 256, 0, stream>>>(lWih, lWhh, Bl);

  for (int s = 0; s < 3; ++s){
    lstm_mm<<<dim3(4, 2), 256, 0, stream>>>(qstar, hl, Bl, gatesL);
    lstm_combine<<<128, 256, 0, stream>>>(gatesL, lbih, lbhh, hl, cl);
    attn_kernel<<<N_GRAPHS, 512, 0, stream>>>(x0, h, hl, qstar);
  }

  out_kernel<<<4*N_GRAPHS, 256, 0, stream>>>(qstar, Wsp, bsp, prelu, (float*)d_out);
}

// Round 5
// 765.594 us; speedup vs baseline: 4.1716x; 1.1572x over previous
//
#include <hip/hip_runtime.h>
#include <math.h>

#define H 64
#define NODE_IN 128
#define EDGE_IN 16
#define N_NODES 40000
#define N_EDGES 80000
#define N_GRAPHS 256
#define READOUT 1024
#define D2 128   // 2H
#define QS 256   // 4H

typedef unsigned short u16;
typedef __attribute__((ext_vector_type(8))) short bf16x8;
typedef __attribute__((ext_vector_type(4))) float f32x4;
#define MFMA16(a,b,c) __builtin_amdgcn_mfma_f32_16x16x32_bf16(a,b,c,0,0,0)

// split-bf16 device globals (static, graph-capture safe)
__device__ u16 d_xhi[N_NODES*H];
__device__ u16 d_xlo[N_NODES*H];
__device__ u16 d_weT_hi[1024*64];
__device__ u16 d_weT_lo[1024*64];
__device__ u16 d_bcT_hi[256*128];
__device__ u16 d_bcT_lo[256*128];

__device__ __forceinline__ float sigmoidf_(float x){ return 1.0f/(1.0f + expf(-x)); }

__device__ __forceinline__ u16 bf_hi(float x){
  union { float f; unsigned u; } c; c.f = x;
  unsigned r = (c.u + 0x7FFFu + ((c.u >> 16) & 1u)) >> 16;
  return (u16)r;
}
__device__ __forceinline__ float bf_f(u16 h){
  union { unsigned u; float f; } c; c.u = ((unsigned)h) << 16; return c.f;
}
__device__ __forceinline__ u16 bf_lo(float x, u16 hi){ return bf_hi(x - bf_f(hi)); }

// ==================== weight packs (once per launch) ====================
__global__ __launch_bounds__(256) void pack_weT(const float* __restrict__ We){
  int i = blockIdx.x*256 + threadIdx.x;     // 65536
  int hh = i >> 10, c = i & 1023;
  float v = We[i];
  u16 hi = bf_hi(v);
  d_weT_hi[c*64 + hh] = hi;
  d_weT_lo[c*64 + hh] = bf_lo(v, hi);
}

__global__ __launch_bounds__(256) void pack_bcT(
    const float* __restrict__ Wih, const float* __restrict__ Whh){
  int i = blockIdx.x*256 + threadIdx.x;     // 32768
  int k = i >> 8, c = i & 255;              // k<128, c<256
  float v;
  if (c < 128){
    v = (k < 64) ? Wih[(size_t)c*H + k] : Whh[(size_t)c*H + (k-64)];
  } else if (c < 192){
    int d = c - 128;
    v = (k < 64) ? Wih[(size_t)(128+d)*H + k] : 0.f;
  } else {
    int d = c - 192;
    v = (k < 64) ? 0.f : Whh[(size_t)(128+d)*H + (k-64)];
  }
  u16 hi = bf_hi(v);
  d_bcT_hi[c*128 + k] = hi;
  d_bcT_lo[c*128 + k] = bf_lo(v, hi);
}

// ==================== proj GEMM: x0 = relu(nf @ Wp^T + bp); h = x0 (+ hi/lo split) ====
__global__ __launch_bounds__(256) void proj_mm(
    const float* __restrict__ nf, const float* __restrict__ Wp,
    const float* __restrict__ bp, float* __restrict__ x0, float* __restrict__ h){
  __shared__ float A_s[NODE_IN][64];
  __shared__ float B_s[NODE_IN][64];
  int t = threadIdx.x;
  int nb = blockIdx.x * 64;
  #pragma unroll
  for (int p = 0; p < 8; ++p){
    int idx = p*256 + t;
    int n = idx >> 5, k4 = idx & 31;
    float4 v = ((const float4*)(nf + (size_t)(nb+n)*NODE_IN))[k4];
    int base = (((n>>2) ^ (k4 & 15)) << 2) + (n & 3);
    A_s[k4*4+0][base]=v.x; A_s[k4*4+1][base]=v.y;
    A_s[k4*4+2][base]=v.z; A_s[k4*4+3][base]=v.w;
  }
  #pragma unroll
  for (int p = 0; p < 8; ++p){
    int idx = p*256 + t;
    int c = idx & 63, k4 = idx >> 6;
    float4 v = ((const float4*)(Wp + (size_t)c*NODE_IN))[k4];
    B_s[k4*4+0][c]=v.x; B_s[k4*4+1][c]=v.y; B_s[k4*4+2][c]=v.z; B_s[k4*4+3][c]=v.w;
  }
  __syncthreads();
  int eg = t & 15, cg = t >> 4;
  float acc[4][4] = {};
  #pragma unroll 4
  for (int k = 0; k < NODE_IN; ++k){
    int s = (k >> 2) & 15;
    float4 a = *(const float4*)&A_s[k][(eg ^ s) << 2];
    float4 b = *(const float4*)&B_s[k][cg*4];
    float av[4] = {a.x,a.y,a.z,a.w};
    float bv[4] = {b.x,b.y,b.z,b.w};
    #pragma unroll
    for (int j = 0; j < 4; ++j)
      #pragma unroll
      for (int c = 0; c < 4; ++c) acc[j][c] += av[j]*bv[c];
  }
  float4 bb = ((const float4*)bp)[cg];
  float bv[4] = {bb.x,bb.y,bb.z,bb.w};
  #pragma unroll
  for (int j = 0; j < 4; ++j){
    int n = nb + eg*4 + j;
    float o[4];
    #pragma unroll
    for (int c = 0; c < 4; ++c) o[c] = fmaxf(acc[j][c]+bv[c], 0.f);
    *(float4*)(x0 + (size_t)n*H + cg*4) = make_float4(o[0],o[1],o[2],o[3]);
    *(float4*)(h  + (size_t)n*H + cg*4) = make_float4(o[0],o[1],o[2],o[3]);
    u16 hs[4], ls[4];
    #pragma unroll
    for (int c = 0; c < 4; ++c){ hs[c] = bf_hi(o[c]); ls[c] = bf_lo(o[c], hs[c]); }
    *(ushort4*)&d_xhi[(size_t)n*H + cg*4] = make_ushort4(hs[0],hs[1],hs[2],hs[3]);
    *(ushort4*)&d_xlo[(size_t)n*H + cg*4] = make_ushort4(ls[0],ls[1],ls[2],ls[3]);
  }
}

// ==================== G GEMM (MFMA split-bf16): G[40000x1024] = x @ We_view ====
// grid (625,4); tile 64 nodes x 256 cols; K=64 in 2 chunks of 32
__global__ __launch_bounds__(256) void g_mm_mfma(float* __restrict__ G){
  __shared__ u16 Ah[64][40], Al[64][40];     // [n][k], pad 40 (80B rows, 16B-aligned)
  __shared__ u16 Bh[256][40], Bl_[256][40];  // [c][k]
  int t = threadIdx.x;
  int w = t >> 6, lane = t & 63;
  int nb = blockIdx.x * 64, cb = blockIdx.y * 256;
  int m = lane & 15, kj = (lane >> 4) * 8;
  f32x4 acc[16];
  #pragma unroll
  for (int i = 0; i < 16; ++i) acc[i] = (f32x4){0.f,0.f,0.f,0.f};
  for (int kc = 0; kc < 2; ++kc){
    __syncthreads();
    { // stage A: 64 rows x 32 k
      int n = t >> 2, q = t & 3;
      int gofs = (nb + n)*H + kc*32 + q*8;
      *(bf16x8*)&Ah[n][q*8] = *(const bf16x8*)&d_xhi[gofs];
      *(bf16x8*)&Al[n][q*8] = *(const bf16x8*)&d_xlo[gofs];
    }
    #pragma unroll
    for (int q = 0; q < 4; ++q){ // stage B^T: 256 c x 32 k
      int gofs = (cb + t)*64 + kc*32 + q*8;
      *(bf16x8*)&Bh[t][q*8]  = *(const bf16x8*)&d_weT_hi[gofs];
      *(bf16x8*)&Bl_[t][q*8] = *(const bf16x8*)&d_weT_lo[gofs];
    }
    __syncthreads();
    bf16x8 ah = *(const bf16x8*)&Ah[w*16 + m][kj];
    bf16x8 al = *(const bf16x8*)&Al[w*16 + m][kj];
    #pragma unroll
    for (int nt = 0; nt < 16; ++nt){
      bf16x8 bh = *(const bf16x8*)&Bh[nt*16 + m][kj];
      bf16x8 bl = *(const bf16x8*)&Bl_[nt*16 + m][kj];
      acc[nt] = MFMA16(ah, bh, acc[nt]);
      acc[nt] = MFMA16(ah, bl, acc[nt]);
      acc[nt] = MFMA16(al, bh, acc[nt]);
    }
  }
  // epilogue: D[r][c]: c = lane&15 (+16*nt), r = (lane>>4)*4 + reg
  int rbase = nb + w*16 + (lane >> 4)*4;
  #pragma unroll
  for (int nt = 0; nt < 16; ++nt){
    int col = cb + nt*16 + (lane & 15);
    #pragma unroll
    for (int r = 0; r < 4; ++r)
      G[(size_t)(rbase + r)*1024 + col] = acc[nt][r];
  }
}

// ==================== P GEMM: P[40000x64] = x @ Bb ====================
__global__ __launch_bounds__(256) void p_mm(
    const float* __restrict__ x, const float* __restrict__ be, float* __restrict__ P){
  __shared__ float A_s[64][64];
  __shared__ float B_s[64][64];
  int t = threadIdx.x;
  int nb = blockIdx.x * 64;
  #pragma unroll
  for (int p = 0; p < 4; ++p){
    int idx = p*256 + t;
    int n = idx >> 4, k4 = idx & 15;
    float4 v = ((const float4*)(x + (size_t)(nb+n)*H))[k4];
    int base = (((n>>2) ^ k4) << 2) + (n & 3);
    A_s[k4*4+0][base]=v.x; A_s[k4*4+1][base]=v.y;
    A_s[k4*4+2][base]=v.z; A_s[k4*4+3][base]=v.w;
  }
  #pragma unroll
  for (int p = 0; p < 4; ++p){
    int idx = p*256 + t;
    int r = idx >> 4, c4 = idx & 15;
    *(float4*)&B_s[r][c4*4] = ((const float4*)(be + (size_t)r*64))[c4];
  }
  __syncthreads();
  int eg = t & 15, cg = t >> 4;
  float acc[4][4] = {};
  #pragma unroll 4
  for (int k = 0; k < 64; ++k){
    int s = (k >> 2) & 15;
    float4 a = *(const float4*)&A_s[k][(eg ^ s) << 2];
    float4 b = *(const float4*)&B_s[k][cg*4];
    float av[4] = {a.x,a.y,a.z,a.w};
    float bv[4] = {b.x,b.y,b.z,b.w};
    #pragma unroll
    for (int j = 0; j < 4; ++j)
      #pragma unroll
      for (int c = 0; c < 4; ++c) acc[j][c] += av[j]*bv[c];
  }
  #pragma unroll
  for (int j = 0; j < 4; ++j){
    int n = nb + eg*4 + j;
    *(float4*)(P + (size_t)n*H + cg*4) =
      make_float4(acc[j][0],acc[j][1],acc[j][2],acc[j][3]);
  }
}

// ==================== edge apply ====================
__global__ __launch_bounds__(256) void edge_apply(
    const float* __restrict__ G, const float* __restrict__ P,
    const float* __restrict__ ef, const int* __restrict__ src,
    const int* __restrict__ dst, float* __restrict__ agg){
  int lane = threadIdx.x & 63;
  int wid = blockIdx.x * 4 + (threadIdx.x >> 6);
  int nw = gridDim.x * 4;
  for (int e = wid; e < N_EDGES; e += nw){
    int s = src[e], d = dst[e];
    const float4* g4 = (const float4*)(G + (size_t)s*1024 + lane*16);
    float4 g0=g4[0], g1=g4[1], g2=g4[2], g3=g4[3];
    const float4* e4 = (const float4*)(ef + (size_t)e*EDGE_IN);
    float4 f0=e4[0], f1=e4[1], f2=e4[2], f3=e4[3];
    float m = P[(size_t)s*H + lane];
    m = fmaf(f0.x,g0.x, fmaf(f0.y,g0.y, fmaf(f0.z,g0.z, fmaf(f0.w,g0.w, m))));
    m = fmaf(f1.x,g1.x, fmaf(f1.y,g1.y, fmaf(f1.z,g1.z, fmaf(f1.w,g1.w, m))));
    m = fmaf(f2.x,g2.x, fmaf(f2.y,g2.y, fmaf(f2.z,g2.z, fmaf(f2.w,g2.w, m))));
    m = fmaf(f3.x,g3.x, fmaf(f3.y,g3.y, fmaf(f3.z,g3.z, fmaf(f3.w,g3.w, m))));
    atomicAdd(&agg[(size_t)d*H + lane], m);
  }
}

// ==================== GRU GEMM (MFMA split-bf16) + fused GRU epilogue ====
// C row = [r_sum(0..63) | z_sum(64..127) | gi_n(128..191) | gh_n(192..255)]
// A = [relu(agg+bconv) k<64 | h k>=64]; writes h and d_xhi/d_xlo
__global__ __launch_bounds__(256) void gru_mm_mfma(
    const float* __restrict__ agg, const float* __restrict__ bconv,
    float* __restrict__ h, const float* __restrict__ gbih,
    const float* __restrict__ gbhh){
  __shared__ u16 Ah[64][40], Al[64][40];
  __shared__ u16 Bh[256][40], Bl_[256][40];
  __shared__ float bih_s[192], bhh_s[192];
  int t = threadIdx.x;
  int w = t >> 6, lane = t & 63;
  int nb = blockIdx.x * 64;
  if (t < 192){ bih_s[t] = gbih[t]; bhh_s[t] = gbhh[t]; }
  int m = lane & 15, kj = (lane >> 4) * 8;
  f32x4 acc[16];
  #pragma unroll
  for (int i = 0; i < 16; ++i) acc[i] = (f32x4){0.f,0.f,0.f,0.f};
  for (int kc = 0; kc < 4; ++kc){
    __syncthreads();
    {
      int n = t >> 2, q = t & 3;
      if (kc < 2){
        const float* sp = agg + (size_t)(nb+n)*H + kc*32 + q*8;
        float4 v0 = *(const float4*)sp;
        float4 v1 = *(const float4*)(sp + 4);
        float4 b0 = *(const float4*)&bconv[kc*32 + q*8];
        float4 b1 = *(const float4*)&bconv[kc*32 + q*8 + 4];
        float vals[8] = { fmaxf(v0.x+b0.x,0.f), fmaxf(v0.y+b0.y,0.f),
                          fmaxf(v0.z+b0.z,0.f), fmaxf(v0.w+b0.w,0.f),
                          fmaxf(v1.x+b1.x,0.f), fmaxf(v1.y+b1.y,0.f),
                          fmaxf(v1.z+b1.z,0.f), fmaxf(v1.w+b1.w,0.f) };
        union { bf16x8 v; u16 u[8]; } ph, pl;
        #pragma unroll
        for (int j = 0; j < 8; ++j){
          u16 hi = bf_hi(vals[j]);
          ph.u[j] = hi; pl.u[j] = bf_lo(vals[j], hi);
        }
        *(bf16x8*)&Ah[n][q*8] = ph.v;
        *(bf16x8*)&Al[n][q*8] = pl.v;
      } else {
        int gofs = (nb+n)*H + (kc-2)*32 + q*8;
        *(bf16x8*)&Ah[n][q*8] = *(const bf16x8*)&d_xhi[gofs];
        *(bf16x8*)&Al[n][q*8] = *(const bf16x8*)&d_xlo[gofs];
      }
    }
    #pragma unroll
    for (int qq = 0; qq < 4; ++qq){
      int gofs = t*128 + kc*32 + qq*8;
      *(bf16x8*)&Bh[t][qq*8]  = *(const bf16x8*)&d_bcT_hi[gofs];
      *(bf16x8*)&Bl_[t][qq*8] = *(const bf16x8*)&d_bcT_lo[gofs];
    }
    __syncthreads();
    bf16x8 ah = *(const bf16x8*)&Ah[w*16 + m][kj];
    bf16x8 al = *(const bf16x8*)&Al[w*16 + m][kj];
    #pragma unroll
    for (int nt = 0; nt < 16; ++nt){
      bf16x8 bh = *(const bf16x8*)&Bh[nt*16 + m][kj];
      bf16x8 bl = *(const bf16x8*)&Bl_[nt*16 + m][kj];
      acc[nt] = MFMA16(ah, bh, acc[nt]);
      acc[nt] = MFMA16(ah, bl, acc[nt]);
      acc[nt] = MFMA16(al, bh, acc[nt]);
    }
  }
  // fused GRU epilogue: gates for (node, d) are all in-lane
  int q4 = lane >> 4, col0 = lane & 15;
  #pragma unroll
  for (int r = 0; r < 4; ++r){
    int node = nb + w*16 + q4*4 + r;
    #pragma unroll
    for (int j = 0; j < 4; ++j){
      int d = col0 + 16*j;
      float rg = sigmoidf_(acc[j][r]   + bih_s[d]      + bhh_s[d]);
      float z  = sigmoidf_(acc[4+j][r] + bih_s[64+d]   + bhh_s[64+d]);
      float nn = tanhf(acc[8+j][r] + bih_s[128+d] + rg*(acc[12+j][r] + bhh_s[128+d]));
      size_t off = (size_t)node*H + d;
      float hv = h[off];
      float hn = (1.f - z)*nn + z*hv;
      h[off] = hn;
      u16 hb = bf_hi(hn);
      d_xhi[off] = hb;
      d_xlo[off] = bf_lo(hn, hb);
    }
  }
}

// ==================== fallback fused edge kernel ====================
__global__ __launch_bounds__(256) void edge_msg_kernel(
    const float* __restrict__ x, const float* __restrict__ ef,
    const int* __restrict__ src, const int* __restrict__ dst,
    const float* __restrict__ We, const float* __restrict__ be,
    float* __restrict__ agg){
  __shared__ float x_s[64][H+1];
  __shared__ float w_s[256][20];
  __shared__ float b_s[256];
  __shared__ int src_s[64], dst_s[64];
  int t = threadIdx.x;
  int ebase = blockIdx.x * 64;
  if (t < 64){ src_s[t] = src[ebase + t]; dst_s[t] = dst[ebase + t]; }
  __syncthreads();
  for (int idx = t; idx < 64*H; idx += 256){
    int e = idx >> 6, hh = idx & 63;
    x_s[e][hh] = x[(size_t)src_s[e]*H + hh];
  }
  int eg = t & 15, og = t >> 4;
  float efr[4][16];
  #pragma unroll
  for (int j = 0; j < 4; ++j){
    const float4* p = (const float4*)(ef + (size_t)(ebase + eg*4 + j)*EDGE_IN);
    #pragma unroll
    for (int q = 0; q < 4; ++q){
      float4 v = p[q];
      efr[j][q*4+0]=v.x; efr[j][q*4+1]=v.y; efr[j][q*4+2]=v.z; efr[j][q*4+3]=v.w;
    }
  }
  float acc[4][4] = {};
  for (int ht = 0; ht < 16; ++ht){
    __syncthreads();
    {
      const float4* wp = (const float4*)(We + (size_t)(ht*256 + t)*EDGE_IN);
      float4 a = wp[0], b = wp[1], c = wp[2], d = wp[3];
      float* wr = w_s[t];
      wr[0]=a.x; wr[1]=a.y; wr[2]=a.z; wr[3]=a.w;
      wr[4]=b.x; wr[5]=b.y; wr[6]=b.z; wr[7]=b.w;
      wr[8]=c.x; wr[9]=c.y; wr[10]=c.z; wr[11]=c.w;
      wr[12]=d.x; wr[13]=d.y; wr[14]=d.z; wr[15]=d.w;
      b_s[t] = be[ht*256 + t];
    }
    __syncthreads();
    #pragma unroll
    for (int hl = 0; hl < 4; ++hl){
      int hglob = ht*4 + hl;
      float xv[4];
      #pragma unroll
      for (int j = 0; j < 4; ++j) xv[j] = x_s[eg*4 + j][hglob];
      #pragma unroll
      for (int oo = 0; oo < 4; ++oo){
        int row = hl*64 + og*4 + oo;
        const float4* wp4 = (const float4*)w_s[row];
        float4 w0 = wp4[0], w1 = wp4[1], w2 = wp4[2], w3 = wp4[3];
        float bb = b_s[row];
        #pragma unroll
        for (int j = 0; j < 4; ++j){
          float d = bb;
          d += efr[j][0]*w0.x + efr[j][1]*w0.y + efr[j][2]*w0.z + efr[j][3]*w0.w;
          d += efr[j][4]*w1.x + efr[j][5]*w1.y + efr[j][6]*w1.z + efr[j][7]*w1.w;
          d += efr[j][8]*w2.x + efr[j][9]*w2.y + efr[j][10]*w2.z + efr[j][11]*w2.w;
          d += efr[j][12]*w3.x + efr[j][13]*w3.y + efr[j][14]*w3.z + efr[j][15]*w3.w;
          acc[j][oo] += xv[j]*d;
        }
      }
    }
  }
  #pragma unroll
  for (int j = 0; j < 4; ++j){
    int dn = dst_s[eg*4 + j];
    #pragma unroll
    for (int oo = 0; oo < 4; ++oo)
      atomicAdd(&agg[(size_t)dn*H + og*4 + oo], acc[j][oo]);
  }
}

// ==================== fallback GRU ====================
__global__ __launch_bounds__(256) void gru_kernel(
    const float* __restrict__ agg, const float* __restrict__ bconv,
    const float* __restrict__ Wih, const float* __restrict__ Whh,
    const float* __restrict__ bih, const float* __restrict__ bhh,
    float* __restrict__ h){
  __shared__ float a_s[4][H], h_s[4][H];
  int t = threadIdx.x;
  int nb = blockIdx.x * 4;
  int nl = t >> 6, d = t & 63;
  int n = nb + nl;
  float av = fmaxf(agg[(size_t)n*H + d] + bconv[d], 0.0f);
  float hv = h[(size_t)n*H + d];
  a_s[nl][d] = av; h_s[nl][d] = hv;
  __syncthreads();
  const float4* av4 = (const float4*)a_s[nl];
  const float4* hv4 = (const float4*)h_s[nl];
  float gi[3], gh[3];
  #pragma unroll
  for (int g = 0; g < 3; ++g){
    int row = g*64 + d;
    const float4* wi = (const float4*)(Wih + (size_t)row*H);
    const float4* wh = (const float4*)(Whh + (size_t)row*H);
    float si = bih[row], sh = bhh[row];
    #pragma unroll
    for (int k4 = 0; k4 < 16; ++k4){
      float4 w1 = wi[k4], w2 = wh[k4];
      float4 aa = av4[k4], hh = hv4[k4];
      si += aa.x*w1.x + aa.y*w1.y + aa.z*w1.z + aa.w*w1.w;
      sh += hh.x*w2.x + hh.y*w2.y + hh.z*w2.z + hh.w*w2.w;
    }
    gi[g] = si; gh[g] = sh;
  }
  float r = sigmoidf_(gi[0] + gh[0]);
  float z = sigmoidf_(gi[1] + gh[1]);
  float nn = tanhf(gi[2] + r*gh[2]);
  h[(size_t)n*H + d] = (1.0f - z)*nn + z*hv;
}

// ==================== Bl pack for LSTM GEMM ====================
__global__ __launch_bounds__(256) void build_bl(
    const float* __restrict__ Wih, const float* __restrict__ Whh,
    float* __restrict__ Bl){
  int i = blockIdx.x*256 + threadIdx.x;   // 196608
  int k = i >> 9, c = i & 511;
  float v = (k < 256) ? Wih[(size_t)c*QS + k] : Whh[(size_t)c*D2 + (k-256)];
  Bl[i] = v;
}

// ==================== LSTM GEMM: gates[256x512] = [qstar|hl] @ Bl ====================
__global__ __launch_bounds__(256) void lstm_mm(
    const float* __restrict__ qstar, const float* __restrict__ hlm,
    const float* __restrict__ Bl, float* __restrict__ gates){
  __shared__ float A_s[32][64];
  __shared__ float B_s[32][256];
  int t = threadIdx.x;
  int mb = blockIdx.x * 64;
  int cb = blockIdx.y * 256;
  int eg = t & 7, cg = t >> 3;
  float acc[8][8] = {};
  for (int kc = 0; kc < 12; ++kc){
    __syncthreads();
    #pragma unroll
    for (int p = 0; p < 2; ++p){
      int idx = p*256 + t;
      int m = idx >> 3, k4 = idx & 7;
      float4 v;
      if (kc < 8)
        v = ((const float4*)(qstar + (size_t)(mb+m)*QS + kc*32))[k4];
      else
        v = ((const float4*)(hlm + (size_t)(mb+m)*D2 + (kc-8)*32))[k4];
      A_s[k4*4+0][m]=v.x; A_s[k4*4+1][m]=v.y; A_s[k4*4+2][m]=v.z; A_s[k4*4+3][m]=v.w;
    }
    #pragma unroll
    for (int p = 0; p < 8; ++p){
      int idx = p*256 + t;
      int r = idx >> 6, c4 = idx & 63;
      *(float4*)&B_s[r][c4*4] = ((const float4*)(Bl + (size_t)(kc*32+r)*512 + cb))[c4];
    }
    __syncthreads();
    #pragma unroll 2
    for (int r = 0; r < 32; ++r){
      float4 a0 = *(const float4*)&A_s[r][eg*8];
      float4 a1 = *(const float4*)&A_s[r][eg*8+4];
      float4 b0 = *(const float4*)&B_s[r][cg*8];
      float4 b1 = *(const float4*)&B_s[r][cg*8+4];
      float av[8] = {a0.x,a0.y,a0.z,a0.w,a1.x,a1.y,a1.z,a1.w};
      float bv[8] = {b0.x,b0.y,b0.z,b0.w,b1.x,b1.y,b1.z,b1.w};
      #pragma unroll
      for (int n = 0; n < 8; ++n)
        #pragma unroll
        for (int c = 0; c < 8; ++c) acc[n][c] += av[n]*bv[c];
    }
  }
  #pragma unroll
  for (int n = 0; n < 8; ++n){
    int g = mb + eg*8 + n;
    float* gp = gates + (size_t)g*512 + cb + cg*8;
    *(float4*)gp       = make_float4(acc[n][0],acc[n][1],acc[n][2],acc[n][3]);
    *(float4*)(gp + 4) = make_float4(acc[n][4],acc[n][5],acc[n][6],acc[n][7]);
  }
}

// ==================== LSTM combine ====================
__global__ __launch_bounds__(256) void lstm_combine(
    const float* __restrict__ gates, const float* __restrict__ bih,
    const float* __restrict__ bhh, float* __restrict__ hl, float* __restrict__ cl){
  int i = blockIdx.x*256 + threadIdx.x;   // 32768
  int g = i >> 7, d = i & 127;
  const float* gr = gates + (size_t)g*512;
  float iv = gr[d]       + bih[d]       + bhh[d];
  float fv = gr[128 + d] + bih[128 + d] + bhh[128 + d];
  float gv = gr[256 + d] + bih[256 + d] + bhh[256 + d];
  float ov = gr[384 + d] + bih[384 + d] + bhh[384 + d];
  float c = sigmoidf_(fv)*cl[(size_t)g*D2 + d] + sigmoidf_(iv)*tanhf(gv);
  float hn = sigmoidf_(ov)*tanhf(c);
  cl[(size_t)g*D2 + d] = c;
  hl[(size_t)g*D2 + d] = hn;
}

// ==================== attention + pooling (512 threads) ====================
__global__ __launch_bounds__(512) void attn_kernel(
    const float* __restrict__ x0, const float* __restrict__ h,
    const float* __restrict__ hl, float* __restrict__ qstar){
  __shared__ float q_s[D2];
  __shared__ float alpha_s[160];
  __shared__ float wred[8];
  __shared__ float part[8][D2];
  int g = blockIdx.x, t = threadIdx.x;
  int lane = t & 63, w = t >> 6;
  int n0 = (g*N_NODES + N_GRAPHS - 1)/N_GRAPHS;
  int n1 = ((g+1)*N_NODES + N_GRAPHS - 1)/N_GRAPHS;
  int cnt = n1 - n0;
  if (t < D2) q_s[t] = hl[(size_t)g*D2 + t];
  __syncthreads();
  float e = -1e30f;
  if (t < cnt){
    int n = n0 + t;
    const float4* xr = (const float4*)(x0 + (size_t)n*H);
    const float4* hr = (const float4*)(h  + (size_t)n*H);
    const float4* q1 = (const float4*)q_s;
    const float4* q2 = (const float4*)(q_s + H);
    float s = 0.0f;
    #pragma unroll
    for (int k4 = 0; k4 < 16; ++k4){
      float4 a = xr[k4], b = q1[k4];
      s += a.x*b.x + a.y*b.y + a.z*b.z + a.w*b.w;
    }
    #pragma unroll
    for (int k4 = 0; k4 < 16; ++k4){
      float4 a = hr[k4], b = q2[k4];
      s += a.x*b.x + a.y*b.y + a.z*b.z + a.w*b.w;
    }
    e = s;
  }
  float m = e;
  #pragma unroll
  for (int off = 32; off >= 1; off >>= 1) m = fmaxf(m, __shfl_xor(m, off));
  if (lane == 0) wred[w] = m;
  __syncthreads();
  float gm = wred[0];
  #pragma unroll
  for (int i = 1; i < 8; ++i) gm = fmaxf(gm, wred[i]);
  __syncthreads();
  float ex = (t < cnt) ? expf(e - gm) : 0.0f;
  float sm = ex;
  #pragma unroll
  for (int off = 32; off >= 1; off >>= 1) sm += __shfl_xor(sm, off);
  if (lane == 0) wred[w] = sm;
  __syncthreads();
  float denom = wred[0]+wred[1]+wred[2]+wred[3]+wred[4]+wred[5]+wred[6]+wred[7];
  if (t < cnt) alpha_s[t] = ex / denom;
  __syncthreads();
  float acc0 = 0.f, acc1 = 0.f;
  for (int i = w; i < cnt; i += 8){
    float a = alpha_s[i];
    acc0 += a * x0[(size_t)(n0+i)*H + lane];
    acc1 += a * h [(size_t)(n0+i)*H + lane];
  }
  part[w][lane]      = acc0;
  part[w][64 + lane] = acc1;
  __syncthreads();
  if (t < D2){
    float v = 0.f;
    #pragma unroll
    for (int i = 0; i < 8; ++i) v += part[i][t];
    qstar[(size_t)g*QS + t]      = q_s[t];
    qstar[(size_t)g*QS + D2 + t] = v;
  }
}

// ==================== readout ====================
__global__ __launch_bounds__(256) void out_kernel(
    const float* __restrict__ qstar, const float* __restrict__ Wsp,
    const float* __restrict__ bsp, const float* __restrict__ prelu,
    float* __restrict__ out){
  __shared__ float q_s[QS];
  int g = blockIdx.x & 255;
  int jb = blockIdx.x >> 8;
  int t = threadIdx.x;
  q_s[t] = qstar[(size_t)g*QS + t];
  __syncthreads();
  int j = jb*256 + t;
  const float4* w = (const float4*)(Wsp + (size_t)j*QS);
  const float4* q4 = (const float4*)q_s;
  float acc = bsp[j];
  #pragma unroll
  for (int k4 = 0; k4 < 64; ++k4){
    float4 wv = w[k4]; float4 qv = q4[k4];
    acc += qv.x*wv.x + qv.y*wv.y + qv.z*wv.z + qv.w*wv.w;
  }
  float pw = prelu[0];
  out[(size_t)g*READOUT + j] = (acc >= 0.0f) ? acc : pw*acc;
}

extern "C" void kernel_launch(void* const* d_in, const int* in_sizes, int n_in,
                              void* d_out, int out_size, void* d_ws, size_t ws_size,
                              hipStream_t stream) {
  const float* node_feats = (const float*)d_in[0];
  const float* edge_feats = (const float*)d_in[1];
  const int*   esrc       = (const int*)d_in[2];
  const int*   edst       = (const int*)d_in[3];
  const float* Wproj = (const float*)d_in[5];
  const float* bproj = (const float*)d_in[6];
  const float* Wedge = (const float*)d_in[7];
  const float* bedge = (const float*)d_in[8];
  const float* bconv = (const float*)d_in[9];
  const float* gWih  = (const float*)d_in[10];
  const float* gWhh  = (const float*)d_in[11];
  const float* gbih  = (const float*)d_in[12];
  const float* gbhh  = (const float*)d_in[13];
  const float* lWih  = (const float*)d_in[14];
  const float* lWhh  = (const float*)d_in[15];
  const float* lbih  = (const float*)d_in[16];
  const float* lbhh  = (const float*)d_in[17];
  const float* Wsp   = (const float*)d_in[18];
  const float* bsp   = (const float*)d_in[19];
  const float* prelu = (const float*)d_in[20];

  float* ws    = (float*)d_ws;
  float* x0    = ws;                     // 2,560,000
  float* h     = ws + 2560000;           // 2,560,000
  float* agg   = ws + 5120000;           // 2,560,000
  float* qstar = ws + 7680000;           // 65,536
  float* hl    = qstar + 65536;          // 32,768
  float* cl    = hl + 32768;             // 32,768
  float* P     = cl + 32768;             // 2,560,000   (ends 10,371,072)
  float* G     = P + 2560000;            // 40,960,000  (ends 51,331,072)
  float* Bl    = agg;                    // s2s phase reuses dead agg
  float* gatesL= agg + 196608;

  const size_t needA = 51331072ull * sizeof(float);  // ~205.3 MB
  int fast = (ws_size >= needA);

  hipMemsetAsync(qstar, 0, (65536 + 32768 + 32768)*sizeof(float), stream);

  if (fast){
    pack_weT<<<256, 256, 0, stream>>>(Wedge);
    pack_bcT<<<128, 256, 0, stream>>>(gWih, gWhh);
  }

  proj_mm<<<N_NODES/64, 256, 0, stream>>>(node_feats, Wproj, bproj, x0, h);

  for (int s = 0; s < 3; ++s){
    if (fast){
      g_mm_mfma<<<dim3(N_NODES/64, 4), 256, 0, stream>>>(G);
      p_mm<<<N_NODES/64, 256, 0, stream>>>(h, bedge, P);
      hipMemsetAsync(agg, 0, (size_t)N_NODES*H*sizeof(float), stream);
      edge_apply<<<2500, 256, 0, stream>>>(G, P, edge_feats, esrc, edst, agg);
      gru_mm_mfma<<<N_NODES/64, 256, 0, stream>>>(agg, bconv, h, gbih, gbhh);
    } else {
      hipMemsetAsync(agg, 0, (size_t)N_NODES*H*sizeof(float), stream);
      edge_msg_kernel<<<N_EDGES/64, 256, 0, stream>>>(h, edge_feats, esrc, edst, Wedge, bedge, agg);
      gru_kernel<<<N_NODES/4, 256, 0, stream>>>(agg, bconv, gWih, gWhh, gbih, gbhh, h);
    }
  }

  build_bl<<<768, 256, 0, stream>>>(lWih, lWhh, Bl);

  for (int s = 0; s < 3; ++s){
    lstm_mm<<<dim3(4, 2), 256, 0, stream>>>(qstar, hl, Bl, gatesL);
    lstm_combine<<<128, 256, 0, stream>>>(gatesL, lbih, lbhh, hl, cl);
    attn_kernel<<<N_GRAPHS, 512, 0, stream>>>(x0, h, hl, qstar);
  }

  out_kernel<<<4*N_GRAPHS, 256, 0, stream>>>(qstar, Wsp, bsp, prelu, (float*)d_out);
}

// Round 6
// 602.434 us; speedup vs baseline: 5.3015x; 1.2708x over previous
//
#include <hip/hip_runtime.h>
#include <math.h>

#define H 64
#define NODE_IN 128
#define EDGE_IN 16
#define N_NODES 40000
#define N_EDGES 80000
#define N_GRAPHS 256
#define READOUT 1024
#define D2 128   // 2H
#define QS 256   // 4H

typedef unsigned short u16;
typedef __attribute__((ext_vector_type(8))) short bf16x8;
typedef __attribute__((ext_vector_type(4))) float f32x4;
#define MFMA16(a,b,c) __builtin_amdgcn_mfma_f32_16x16x32_bf16(a,b,c,0,0,0)

// split-bf16 device globals (static, graph-capture safe)
__device__ u16 d_xhi[N_NODES*H];
__device__ u16 d_xlo[N_NODES*H];
__device__ u16 d_weT_hi[1024*64];
__device__ u16 d_weT_lo[1024*64];
__device__ u16 d_bcT_hi[256*128];
__device__ u16 d_bcT_lo[256*128];

__device__ __forceinline__ float sigmoidf_(float x){ return 1.0f/(1.0f + expf(-x)); }

__device__ __forceinline__ u16 bf_hi(float x){
  union { float f; unsigned u; } c; c.f = x;
  unsigned r = (c.u + 0x7FFFu + ((c.u >> 16) & 1u)) >> 16;
  return (u16)r;
}
__device__ __forceinline__ float bf_f(u16 h){
  union { unsigned u; float f; } c; c.u = ((unsigned)h) << 16; return c.f;
}
__device__ __forceinline__ u16 bf_lo(float x, u16 hi){ return bf_hi(x - bf_f(hi)); }

// ==================== weight packs (once per launch) ====================
__global__ __launch_bounds__(256) void pack_weT(const float* __restrict__ We){
  int i = blockIdx.x*256 + threadIdx.x;     // 65536
  int hh = i >> 10, c = i & 1023;
  float v = We[i];
  u16 hi = bf_hi(v);
  d_weT_hi[c*64 + hh] = hi;
  d_weT_lo[c*64 + hh] = bf_lo(v, hi);
}

__global__ __launch_bounds__(256) void pack_bcT(
    const float* __restrict__ Wih, const float* __restrict__ Whh){
  int i = blockIdx.x*256 + threadIdx.x;     // 32768
  int k = i >> 8, c = i & 255;              // k<128, c<256
  float v;
  if (c < 128){
    v = (k < 64) ? Wih[(size_t)c*H + k] : Whh[(size_t)c*H + (k-64)];
  } else if (c < 192){
    int d = c - 128;
    v = (k < 64) ? Wih[(size_t)(128+d)*H + k] : 0.f;
  } else {
    int d = c - 192;
    v = (k < 64) ? 0.f : Whh[(size_t)(128+d)*H + (k-64)];
  }
  u16 hi = bf_hi(v);
  d_bcT_hi[c*128 + k] = hi;
  d_bcT_lo[c*128 + k] = bf_lo(v, hi);
}

// ==================== proj GEMM: x0 = relu(nf @ Wp^T + bp); h = x0 (+ hi/lo split) ====
__global__ __launch_bounds__(256) void proj_mm(
    const float* __restrict__ nf, const float* __restrict__ Wp,
    const float* __restrict__ bp, float* __restrict__ x0, float* __restrict__ h){
  __shared__ float A_s[NODE_IN][64];
  __shared__ float B_s[NODE_IN][64];
  int t = threadIdx.x;
  int nb = blockIdx.x * 64;
  #pragma unroll
  for (int p = 0; p < 8; ++p){
    int idx = p*256 + t;
    int n = idx >> 5, k4 = idx & 31;
    float4 v = ((const float4*)(nf + (size_t)(nb+n)*NODE_IN))[k4];
    int base = (((n>>2) ^ (k4 & 15)) << 2) + (n & 3);
    A_s[k4*4+0][base]=v.x; A_s[k4*4+1][base]=v.y;
    A_s[k4*4+2][base]=v.z; A_s[k4*4+3][base]=v.w;
  }
  #pragma unroll
  for (int p = 0; p < 8; ++p){
    int idx = p*256 + t;
    int c = idx & 63, k4 = idx >> 6;
    float4 v = ((const float4*)(Wp + (size_t)c*NODE_IN))[k4];
    B_s[k4*4+0][c]=v.x; B_s[k4*4+1][c]=v.y; B_s[k4*4+2][c]=v.z; B_s[k4*4+3][c]=v.w;
  }
  __syncthreads();
  int eg = t & 15, cg = t >> 4;
  float acc[4][4] = {};
  #pragma unroll 4
  for (int k = 0; k < NODE_IN; ++k){
    int s = (k >> 2) & 15;
    float4 a = *(const float4*)&A_s[k][(eg ^ s) << 2];
    float4 b = *(const float4*)&B_s[k][cg*4];
    float av[4] = {a.x,a.y,a.z,a.w};
    float bv[4] = {b.x,b.y,b.z,b.w};
    #pragma unroll
    for (int j = 0; j < 4; ++j)
      #pragma unroll
      for (int c = 0; c < 4; ++c) acc[j][c] += av[j]*bv[c];
  }
  float4 bb = ((const float4*)bp)[cg];
  float bv[4] = {bb.x,bb.y,bb.z,bb.w};
  #pragma unroll
  for (int j = 0; j < 4; ++j){
    int n = nb + eg*4 + j;
    float o[4];
    #pragma unroll
    for (int c = 0; c < 4; ++c) o[c] = fmaxf(acc[j][c]+bv[c], 0.f);
    *(float4*)(x0 + (size_t)n*H + cg*4) = make_float4(o[0],o[1],o[2],o[3]);
    *(float4*)(h  + (size_t)n*H + cg*4) = make_float4(o[0],o[1],o[2],o[3]);
    u16 hs[4], ls[4];
    #pragma unroll
    for (int c = 0; c < 4; ++c){ hs[c] = bf_hi(o[c]); ls[c] = bf_lo(o[c], hs[c]); }
    *(ushort4*)&d_xhi[(size_t)n*H + cg*4] = make_ushort4(hs[0],hs[1],hs[2],hs[3]);
    *(ushort4*)&d_xlo[(size_t)n*H + cg*4] = make_ushort4(ls[0],ls[1],ls[2],ls[3]);
  }
}

// ==================== G GEMM (MFMA split-bf16): G[40000x1024] = x @ We_view ====
__global__ __launch_bounds__(256) void g_mm_mfma(float* __restrict__ G){
  __shared__ u16 Ah[64][40], Al[64][40];
  __shared__ u16 Bh[256][40], Bl_[256][40];
  int t = threadIdx.x;
  int w = t >> 6, lane = t & 63;
  int nb = blockIdx.x * 64, cb = blockIdx.y * 256;
  int m = lane & 15, kj = (lane >> 4) * 8;
  f32x4 acc[16];
  #pragma unroll
  for (int i = 0; i < 16; ++i) acc[i] = (f32x4){0.f,0.f,0.f,0.f};
  for (int kc = 0; kc < 2; ++kc){
    __syncthreads();
    {
      int n = t >> 2, q = t & 3;
      int gofs = (nb + n)*H + kc*32 + q*8;
      *(bf16x8*)&Ah[n][q*8] = *(const bf16x8*)&d_xhi[gofs];
      *(bf16x8*)&Al[n][q*8] = *(const bf16x8*)&d_xlo[gofs];
    }
    #pragma unroll
    for (int q = 0; q < 4; ++q){
      int gofs = (cb + t)*64 + kc*32 + q*8;
      *(bf16x8*)&Bh[t][q*8]  = *(const bf16x8*)&d_weT_hi[gofs];
      *(bf16x8*)&Bl_[t][q*8] = *(const bf16x8*)&d_weT_lo[gofs];
    }
    __syncthreads();
    bf16x8 ah = *(const bf16x8*)&Ah[w*16 + m][kj];
    bf16x8 al = *(const bf16x8*)&Al[w*16 + m][kj];
    #pragma unroll
    for (int nt = 0; nt < 16; ++nt){
      bf16x8 bh = *(const bf16x8*)&Bh[nt*16 + m][kj];
      bf16x8 bl = *(const bf16x8*)&Bl_[nt*16 + m][kj];
      acc[nt] = MFMA16(ah, bh, acc[nt]);
      acc[nt] = MFMA16(ah, bl, acc[nt]);
      acc[nt] = MFMA16(al, bh, acc[nt]);
    }
  }
  int rbase = nb + w*16 + (lane >> 4)*4;
  #pragma unroll
  for (int nt = 0; nt < 16; ++nt){
    int col = cb + nt*16 + (lane & 15);
    #pragma unroll
    for (int r = 0; r < 4; ++r)
      G[(size_t)(rbase + r)*1024 + col] = acc[nt][r];
  }
}

// ==================== P GEMM: P[40000x64] = x @ Bb ====================
__global__ __launch_bounds__(256) void p_mm(
    const float* __restrict__ x, const float* __restrict__ be, float* __restrict__ P){
  __shared__ float A_s[64][64];
  __shared__ float B_s[64][64];
  int t = threadIdx.x;
  int nb = blockIdx.x * 64;
  #pragma unroll
  for (int p = 0; p < 4; ++p){
    int idx = p*256 + t;
    int n = idx >> 4, k4 = idx & 15;
    float4 v = ((const float4*)(x + (size_t)(nb+n)*H))[k4];
    int base = (((n>>2) ^ k4) << 2) + (n & 3);
    A_s[k4*4+0][base]=v.x; A_s[k4*4+1][base]=v.y;
    A_s[k4*4+2][base]=v.z; A_s[k4*4+3][base]=v.w;
  }
  #pragma unroll
  for (int p = 0; p < 4; ++p){
    int idx = p*256 + t;
    int r = idx >> 4, c4 = idx & 15;
    *(float4*)&B_s[r][c4*4] = ((const float4*)(be + (size_t)r*64))[c4];
  }
  __syncthreads();
  int eg = t & 15, cg = t >> 4;
  float acc[4][4] = {};
  #pragma unroll 4
  for (int k = 0; k < 64; ++k){
    int s = (k >> 2) & 15;
    float4 a = *(const float4*)&A_s[k][(eg ^ s) << 2];
    float4 b = *(const float4*)&B_s[k][cg*4];
    float av[4] = {a.x,a.y,a.z,a.w};
    float bv[4] = {b.x,b.y,b.z,b.w};
    #pragma unroll
    for (int j = 0; j < 4; ++j)
      #pragma unroll
      for (int c = 0; c < 4; ++c) acc[j][c] += av[j]*bv[c];
  }
  #pragma unroll
  for (int j = 0; j < 4; ++j){
    int n = nb + eg*4 + j;
    *(float4*)(P + (size_t)n*H + cg*4) =
      make_float4(acc[j][0],acc[j][1],acc[j][2],acc[j][3]);
  }
}

// ==================== edge apply ====================
__global__ __launch_bounds__(256) void edge_apply(
    const float* __restrict__ G, const float* __restrict__ P,
    const float* __restrict__ ef, const int* __restrict__ src,
    const int* __restrict__ dst, float* __restrict__ agg){
  int lane = threadIdx.x & 63;
  int wid = blockIdx.x * 4 + (threadIdx.x >> 6);
  int nw = gridDim.x * 4;
  for (int e = wid; e < N_EDGES; e += nw){
    int s = src[e], d = dst[e];
    const float4* g4 = (const float4*)(G + (size_t)s*1024 + lane*16);
    float4 g0=g4[0], g1=g4[1], g2=g4[2], g3=g4[3];
    const float4* e4 = (const float4*)(ef + (size_t)e*EDGE_IN);
    float4 f0=e4[0], f1=e4[1], f2=e4[2], f3=e4[3];
    float m = P[(size_t)s*H + lane];
    m = fmaf(f0.x,g0.x, fmaf(f0.y,g0.y, fmaf(f0.z,g0.z, fmaf(f0.w,g0.w, m))));
    m = fmaf(f1.x,g1.x, fmaf(f1.y,g1.y, fmaf(f1.z,g1.z, fmaf(f1.w,g1.w, m))));
    m = fmaf(f2.x,g2.x, fmaf(f2.y,g2.y, fmaf(f2.z,g2.z, fmaf(f2.w,g2.w, m))));
    m = fmaf(f3.x,g3.x, fmaf(f3.y,g3.y, fmaf(f3.z,g3.z, fmaf(f3.w,g3.w, m))));
    atomicAdd(&agg[(size_t)d*H + lane], m);
  }
}

// ==================== GRU GEMM (MFMA split-bf16) + fused GRU epilogue ====
__global__ __launch_bounds__(256) void gru_mm_mfma(
    const float* __restrict__ agg, const float* __restrict__ bconv,
    float* __restrict__ h, const float* __restrict__ gbih,
    const float* __restrict__ gbhh){
  __shared__ u16 Ah[64][40], Al[64][40];
  __shared__ u16 Bh[256][40], Bl_[256][40];
  __shared__ float bih_s[192], bhh_s[192];
  int t = threadIdx.x;
  int w = t >> 6, lane = t & 63;
  int nb = blockIdx.x * 64;
  if (t < 192){ bih_s[t] = gbih[t]; bhh_s[t] = gbhh[t]; }
  int m = lane & 15, kj = (lane >> 4) * 8;
  f32x4 acc[16];
  #pragma unroll
  for (int i = 0; i < 16; ++i) acc[i] = (f32x4){0.f,0.f,0.f,0.f};
  for (int kc = 0; kc < 4; ++kc){
    __syncthreads();
    {
      int n = t >> 2, q = t & 3;
      if (kc < 2){
        const float* sp = agg + (size_t)(nb+n)*H + kc*32 + q*8;
        float4 v0 = *(const float4*)sp;
        float4 v1 = *(const float4*)(sp + 4);
        float4 b0 = *(const float4*)&bconv[kc*32 + q*8];
        float4 b1 = *(const float4*)&bconv[kc*32 + q*8 + 4];
        float vals[8] = { fmaxf(v0.x+b0.x,0.f), fmaxf(v0.y+b0.y,0.f),
                          fmaxf(v0.z+b0.z,0.f), fmaxf(v0.w+b0.w,0.f),
                          fmaxf(v1.x+b1.x,0.f), fmaxf(v1.y+b1.y,0.f),
                          fmaxf(v1.z+b1.z,0.f), fmaxf(v1.w+b1.w,0.f) };
        union { bf16x8 v; u16 u[8]; } ph, pl;
        #pragma unroll
        for (int j = 0; j < 8; ++j){
          u16 hi = bf_hi(vals[j]);
          ph.u[j] = hi; pl.u[j] = bf_lo(vals[j], hi);
        }
        *(bf16x8*)&Ah[n][q*8] = ph.v;
        *(bf16x8*)&Al[n][q*8] = pl.v;
      } else {
        int gofs = (nb+n)*H + (kc-2)*32 + q*8;
        *(bf16x8*)&Ah[n][q*8] = *(const bf16x8*)&d_xhi[gofs];
        *(bf16x8*)&Al[n][q*8] = *(const bf16x8*)&d_xlo[gofs];
      }
    }
    #pragma unroll
    for (int qq = 0; qq < 4; ++qq){
      int gofs = t*128 + kc*32 + qq*8;
      *(bf16x8*)&Bh[t][qq*8]  = *(const bf16x8*)&d_bcT_hi[gofs];
      *(bf16x8*)&Bl_[t][qq*8] = *(const bf16x8*)&d_bcT_lo[gofs];
    }
    __syncthreads();
    bf16x8 ah = *(const bf16x8*)&Ah[w*16 + m][kj];
    bf16x8 al = *(const bf16x8*)&Al[w*16 + m][kj];
    #pragma unroll
    for (int nt = 0; nt < 16; ++nt){
      bf16x8 bh = *(const bf16x8*)&Bh[nt*16 + m][kj];
      bf16x8 bl = *(const bf16x8*)&Bl_[nt*16 + m][kj];
      acc[nt] = MFMA16(ah, bh, acc[nt]);
      acc[nt] = MFMA16(ah, bl, acc[nt]);
      acc[nt] = MFMA16(al, bh, acc[nt]);
    }
  }
  int q4 = lane >> 4, col0 = lane & 15;
  #pragma unroll
  for (int r = 0; r < 4; ++r){
    int node = nb + w*16 + q4*4 + r;
    #pragma unroll
    for (int j = 0; j < 4; ++j){
      int d = col0 + 16*j;
      float rg = sigmoidf_(acc[j][r]   + bih_s[d]      + bhh_s[d]);
      float z  = sigmoidf_(acc[4+j][r] + bih_s[64+d]   + bhh_s[64+d]);
      float nn = tanhf(acc[8+j][r] + bih_s[128+d] + rg*(acc[12+j][r] + bhh_s[128+d]));
      size_t off = (size_t)node*H + d;
      float hv = h[off];
      float hn = (1.f - z)*nn + z*hv;
      h[off] = hn;
      u16 hb = bf_hi(hn);
      d_xhi[off] = hb;
      d_xlo[off] = bf_lo(hn, hb);
    }
  }
}

// ==================== fallback fused edge kernel ====================
__global__ __launch_bounds__(256) void edge_msg_kernel(
    const float* __restrict__ x, const float* __restrict__ ef,
    const int* __restrict__ src, const int* __restrict__ dst,
    const float* __restrict__ We, const float* __restrict__ be,
    float* __restrict__ agg){
  __shared__ float x_s[64][H+1];
  __shared__ float w_s[256][20];
  __shared__ float b_s[256];
  __shared__ int src_s[64], dst_s[64];
  int t = threadIdx.x;
  int ebase = blockIdx.x * 64;
  if (t < 64){ src_s[t] = src[ebase + t]; dst_s[t] = dst[ebase + t]; }
  __syncthreads();
  for (int idx = t; idx < 64*H; idx += 256){
    int e = idx >> 6, hh = idx & 63;
    x_s[e][hh] = x[(size_t)src_s[e]*H + hh];
  }
  int eg = t & 15, og = t >> 4;
  float efr[4][16];
  #pragma unroll
  for (int j = 0; j < 4; ++j){
    const float4* p = (const float4*)(ef + (size_t)(ebase + eg*4 + j)*EDGE_IN);
    #pragma unroll
    for (int q = 0; q < 4; ++q){
      float4 v = p[q];
      efr[j][q*4+0]=v.x; efr[j][q*4+1]=v.y; efr[j][q*4+2]=v.z; efr[j][q*4+3]=v.w;
    }
  }
  float acc[4][4] = {};
  for (int ht = 0; ht < 16; ++ht){
    __syncthreads();
    {
      const float4* wp = (const float4*)(We + (size_t)(ht*256 + t)*EDGE_IN);
      float4 a = wp[0], b = wp[1], c = wp[2], d = wp[3];
      float* wr = w_s[t];
      wr[0]=a.x; wr[1]=a.y; wr[2]=a.z; wr[3]=a.w;
      wr[4]=b.x; wr[5]=b.y; wr[6]=b.z; wr[7]=b.w;
      wr[8]=c.x; wr[9]=c.y; wr[10]=c.z; wr[11]=c.w;
      wr[12]=d.x; wr[13]=d.y; wr[14]=d.z; wr[15]=d.w;
      b_s[t] = be[ht*256 + t];
    }
    __syncthreads();
    #pragma unroll
    for (int hl = 0; hl < 4; ++hl){
      int hglob = ht*4 + hl;
      float xv[4];
      #pragma unroll
      for (int j = 0; j < 4; ++j) xv[j] = x_s[eg*4 + j][hglob];
      #pragma unroll
      for (int oo = 0; oo < 4; ++oo){
        int row = hl*64 + og*4 + oo;
        const float4* wp4 = (const float4*)w_s[row];
        float4 w0 = wp4[0], w1 = wp4[1], w2 = wp4[2], w3 = wp4[3];
        float bb = b_s[row];
        #pragma unroll
        for (int j = 0; j < 4; ++j){
          float d = bb;
          d += efr[j][0]*w0.x + efr[j][1]*w0.y + efr[j][2]*w0.z + efr[j][3]*w0.w;
          d += efr[j][4]*w1.x + efr[j][5]*w1.y + efr[j][6]*w1.z + efr[j][7]*w1.w;
          d += efr[j][8]*w2.x + efr[j][9]*w2.y + efr[j][10]*w2.z + efr[j][11]*w2.w;
          d += efr[j][12]*w3.x + efr[j][13]*w3.y + efr[j][14]*w3.z + efr[j][15]*w3.w;
          acc[j][oo] += xv[j]*d;
        }
      }
    }
  }
  #pragma unroll
  for (int j = 0; j < 4; ++j){
    int dn = dst_s[eg*4 + j];
    #pragma unroll
    for (int oo = 0; oo < 4; ++oo)
      atomicAdd(&agg[(size_t)dn*H + og*4 + oo], acc[j][oo]);
  }
}

// ==================== fallback GRU ====================
__global__ __launch_bounds__(256) void gru_kernel(
    const float* __restrict__ agg, const float* __restrict__ bconv,
    const float* __restrict__ Wih, const float* __restrict__ Whh,
    const float* __restrict__ bih, const float* __restrict__ bhh,
    float* __restrict__ h){
  __shared__ float a_s[4][H], h_s[4][H];
  int t = threadIdx.x;
  int nb = blockIdx.x * 4;
  int nl = t >> 6, d = t & 63;
  int n = nb + nl;
  float av = fmaxf(agg[(size_t)n*H + d] + bconv[d], 0.0f);
  float hv = h[(size_t)n*H + d];
  a_s[nl][d] = av; h_s[nl][d] = hv;
  __syncthreads();
  const float4* av4 = (const float4*)a_s[nl];
  const float4* hv4 = (const float4*)h_s[nl];
  float gi[3], gh[3];
  #pragma unroll
  for (int g = 0; g < 3; ++g){
    int row = g*64 + d;
    const float4* wi = (const float4*)(Wih + (size_t)row*H);
    const float4* wh = (const float4*)(Whh + (size_t)row*H);
    float si = bih[row], sh = bhh[row];
    #pragma unroll
    for (int k4 = 0; k4 < 16; ++k4){
      float4 w1 = wi[k4], w2 = wh[k4];
      float4 aa = av4[k4], hh = hv4[k4];
      si += aa.x*w1.x + aa.y*w1.y + aa.z*w1.z + aa.w*w1.w;
      sh += hh.x*w2.x + hh.y*w2.y + hh.z*w2.z + hh.w*w2.w;
    }
    gi[g] = si; gh[g] = sh;
  }
  float r = sigmoidf_(gi[0] + gh[0]);
  float z = sigmoidf_(gi[1] + gh[1]);
  float nn = tanhf(gi[2] + r*gh[2]);
  h[(size_t)n*H + d] = (1.0f - z)*nn + z*hv;
}

// ==================== Bl2 pack: gate-interleaved transposed LSTM weights ====
// Bl2[k][4d+gate] ; k<384 (256 qstar | 128 hl), d<128, gate in i|f|g|o
__global__ __launch_bounds__(256) void build_bl2(
    const float* __restrict__ Wih, const float* __restrict__ Whh,
    float* __restrict__ Bl2){
  int i = blockIdx.x*256 + threadIdx.x;   // 196608
  int k = i >> 9, c = i & 511;
  int d = c >> 2, gate = c & 3;
  int row = gate*128 + d;
  float v = (k < 256) ? Wih[(size_t)row*QS + k] : Whh[(size_t)row*D2 + (k-256)];
  Bl2[i] = v;
}

// ==================== fused LSTM cell: 1 block/graph, 1 thread/d ====
// gates(g,d) = sum_k A[g,k]*Bl2[k][4d+*] ; then c/h update in-thread
__global__ __launch_bounds__(128) void lstm_fused(
    const float* __restrict__ qstar, const float* __restrict__ Bl2,
    const float* __restrict__ bih, const float* __restrict__ bhh,
    float* __restrict__ hl, float* __restrict__ cl){
  __shared__ float A_s[384];
  int g = blockIdx.x, t = threadIdx.x;
  A_s[t]       = qstar[(size_t)g*QS + t];
  A_s[128 + t] = qstar[(size_t)g*QS + 128 + t];
  A_s[256 + t] = hl[(size_t)g*D2 + t];
  __syncthreads();
  float ai = 0.f, af = 0.f, ag = 0.f, ao = 0.f;
  const float* bp = Bl2 + 4*t;
  #pragma unroll 8
  for (int k = 0; k < 384; ++k){
    float a = A_s[k];
    float4 b = *(const float4*)(bp + (size_t)k*512);
    ai += a*b.x; af += a*b.y; ag += a*b.z; ao += a*b.w;
  }
  float iv = ai + bih[t]       + bhh[t];
  float fv = af + bih[128 + t] + bhh[128 + t];
  float gv = ag + bih[256 + t] + bhh[256 + t];
  float ov = ao + bih[384 + t] + bhh[384 + t];
  float c = sigmoidf_(fv)*cl[(size_t)g*D2 + t] + sigmoidf_(iv)*tanhf(gv);
  float hn = sigmoidf_(ov)*tanhf(c);
  cl[(size_t)g*D2 + t] = c;
  hl[(size_t)g*D2 + t] = hn;
}

// ==================== attention + pooling (512 threads) ====================
__global__ __launch_bounds__(512) void attn_kernel(
    const float* __restrict__ x0, const float* __restrict__ h,
    const float* __restrict__ hl, float* __restrict__ qstar){
  __shared__ float q_s[D2];
  __shared__ float alpha_s[160];
  __shared__ float wred[8];
  __shared__ float part[8][D2];
  int g = blockIdx.x, t = threadIdx.x;
  int lane = t & 63, w = t >> 6;
  int n0 = (g*N_NODES + N_GRAPHS - 1)/N_GRAPHS;
  int n1 = ((g+1)*N_NODES + N_GRAPHS - 1)/N_GRAPHS;
  int cnt = n1 - n0;
  if (t < D2) q_s[t] = hl[(size_t)g*D2 + t];
  __syncthreads();
  float e = -1e30f;
  if (t < cnt){
    int n = n0 + t;
    const float4* xr = (const float4*)(x0 + (size_t)n*H);
    const float4* hr = (const float4*)(h  + (size_t)n*H);
    const float4* q1 = (const float4*)q_s;
    const float4* q2 = (const float4*)(q_s + H);
    float s = 0.0f;
    #pragma unroll
    for (int k4 = 0; k4 < 16; ++k4){
      float4 a = xr[k4], b = q1[k4];
      s += a.x*b.x + a.y*b.y + a.z*b.z + a.w*b.w;
    }
    #pragma unroll
    for (int k4 = 0; k4 < 16; ++k4){
      float4 a = hr[k4], b = q2[k4];
      s += a.x*b.x + a.y*b.y + a.z*b.z + a.w*b.w;
    }
    e = s;
  }
  float m = e;
  #pragma unroll
  for (int off = 32; off >= 1; off >>= 1) m = fmaxf(m, __shfl_xor(m, off));
  if (lane == 0) wred[w] = m;
  __syncthreads();
  float gm = wred[0];
  #pragma unroll
  for (int i = 1; i < 8; ++i) gm = fmaxf(gm, wred[i]);
  __syncthreads();
  float ex = (t < cnt) ? expf(e - gm) : 0.0f;
  float sm = ex;
  #pragma unroll
  for (int off = 32; off >= 1; off >>= 1) sm += __shfl_xor(sm, off);
  if (lane == 0) wred[w] = sm;
  __syncthreads();
  float denom = wred[0]+wred[1]+wred[2]+wred[3]+wred[4]+wred[5]+wred[6]+wred[7];
  if (t < cnt) alpha_s[t] = ex / denom;
  __syncthreads();
  float acc0 = 0.f, acc1 = 0.f;
  for (int i = w; i < cnt; i += 8){
    float a = alpha_s[i];
    acc0 += a * x0[(size_t)(n0+i)*H + lane];
    acc1 += a * h [(size_t)(n0+i)*H + lane];
  }
  part[w][lane]      = acc0;
  part[w][64 + lane] = acc1;
  __syncthreads();
  if (t < D2){
    float v = 0.f;
    #pragma unroll
    for (int i = 0; i < 8; ++i) v += part[i][t];
    qstar[(size_t)g*QS + t]      = q_s[t];
    qstar[(size_t)g*QS + D2 + t] = v;
  }
}

// ==================== readout ====================
__global__ __launch_bounds__(256) void out_kernel(
    const float* __restrict__ qstar, const float* __restrict__ Wsp,
    const float* __restrict__ bsp, const float* __restrict__ prelu,
    float* __restrict__ out){
  __shared__ float q_s[QS];
  int g = blockIdx.x & 255;
  int jb = blockIdx.x >> 8;
  int t = threadIdx.x;
  q_s[t] = qstar[(size_t)g*QS + t];
  __syncthreads();
  int j = jb*256 + t;
  const float4* w = (const float4*)(Wsp + (size_t)j*QS);
  const float4* q4 = (const float4*)q_s;
  float acc = bsp[j];
  #pragma unroll
  for (int k4 = 0; k4 < 64; ++k4){
    float4 wv = w[k4]; float4 qv = q4[k4];
    acc += qv.x*wv.x + qv.y*wv.y + qv.z*wv.z + qv.w*wv.w;
  }
  float pw = prelu[0];
  out[(size_t)g*READOUT + j] = (acc >= 0.0f) ? acc : pw*acc;
}

extern "C" void kernel_launch(void* const* d_in, const int* in_sizes, int n_in,
                              void* d_out, int out_size, void* d_ws, size_t ws_size,
                              hipStream_t stream) {
  const float* node_feats = (const float*)d_in[0];
  const float* edge_feats = (const float*)d_in[1];
  const int*   esrc       = (const int*)d_in[2];
  const int*   edst       = (const int*)d_in[3];
  const float* Wproj = (const float*)d_in[5];
  const float* bproj = (const float*)d_in[6];
  const float* Wedge = (const float*)d_in[7];
  const float* bedge = (const float*)d_in[8];
  const float* bconv = (const float*)d_in[9];
  const float* gWih  = (const float*)d_in[10];
  const float* gWhh  = (const float*)d_in[11];
  const float* gbih  = (const float*)d_in[12];
  const float* gbhh  = (const float*)d_in[13];
  const float* lWih  = (const float*)d_in[14];
  const float* lWhh  = (const float*)d_in[15];
  const float* lbih  = (const float*)d_in[16];
  const float* lbhh  = (const float*)d_in[17];
  const float* Wsp   = (const float*)d_in[18];
  const float* bsp   = (const float*)d_in[19];
  const float* prelu = (const float*)d_in[20];

  float* ws    = (float*)d_ws;
  float* x0    = ws;                     // 2,560,000
  float* h     = ws + 2560000;           // 2,560,000
  float* agg   = ws + 5120000;           // 2,560,000
  float* qstar = ws + 7680000;           // 65,536
  float* hl    = qstar + 65536;          // 32,768
  float* cl    = hl + 32768;             // 32,768
  float* P     = cl + 32768;             // 2,560,000   (ends 10,371,072)
  float* G     = P + 2560000;            // 40,960,000  (ends 51,331,072)
  float* Bl2   = agg;                    // s2s phase reuses dead agg (196,608)

  const size_t needA = 51331072ull * sizeof(float);  // ~205.3 MB
  int fast = (ws_size >= needA);

  hipMemsetAsync(qstar, 0, (65536 + 32768 + 32768)*sizeof(float), stream);

  if (fast){
    pack_weT<<<256, 256, 0, stream>>>(Wedge);
    pack_bcT<<<128, 256, 0, stream>>>(gWih, gWhh);
  }

  proj_mm<<<N_NODES/64, 256, 0, stream>>>(node_feats, Wproj, bproj, x0, h);

  for (int s = 0; s < 3; ++s){
    if (fast){
      g_mm_mfma<<<dim3(N_NODES/64, 4), 256, 0, stream>>>(G);
      p_mm<<<N_NODES/64, 256, 0, stream>>>(h, bedge, P);
      hipMemsetAsync(agg, 0, (size_t)N_NODES*H*sizeof(float), stream);
      edge_apply<<<2500, 256, 0, stream>>>(G, P, edge_feats, esrc, edst, agg);
      gru_mm_mfma<<<N_NODES/64, 256, 0, stream>>>(agg, bconv, h, gbih, gbhh);
    } else {
      hipMemsetAsync(agg, 0, (size_t)N_NODES*H*sizeof(float), stream);
      edge_msg_kernel<<<N_EDGES/64, 256, 0, stream>>>(h, edge_feats, esrc, edst, Wedge, bedge, agg);
      gru_kernel<<<N_NODES/4, 256, 0, stream>>>(agg, bconv, gWih, gWhh, gbih, gbhh, h);
    }
  }

  build_bl2<<<768, 256, 0, stream>>>(lWih, lWhh, Bl2);

  for (int s = 0; s < 3; ++s){
    lstm_fused<<<N_GRAPHS, 128, 0, stream>>>(qstar, Bl2, lbih, lbhh, hl, cl);
    attn_kernel<<<N_GRAPHS, 512, 0, stream>>>(x0, h, hl, qstar);
  }

  out_kernel<<<4*N_GRAPHS, 256, 0, stream>>>(qstar, Wsp, bsp, prelu, (float*)d_out);
}